// Round 4
// baseline (1021.150 us; speedup 1.0000x reference)
//
#include <hip/hip_runtime.h>
#include <hip/hip_bf16.h>
#include <math.h>

// Problem constants
#define B_  4
#define S_  512
#define H_  768
#define NH_ 12
#define DH_ 64
#define FF_ 3072
#define L_  6
#define V_  30522
#define QKVN 2304          // fused QKV output width
#define M_  (B_ * S_)      // 2048 tokens

typedef short s16x8 __attribute__((ext_vector_type(8)));
typedef short s16x4v __attribute__((ext_vector_type(4)));
typedef float f32x4 __attribute__((ext_vector_type(4)));

__device__ __forceinline__ void gload_lds16(const void* g, void* l) {
    __builtin_amdgcn_global_load_lds(
        (const __attribute__((address_space(1))) void*)g,
        (__attribute__((address_space(3))) void*)l,
        16, 0, 0);
}

__device__ __forceinline__ ushort f2bu(float x) {
    __hip_bfloat16 h = __float2bfloat16(x);
    return *(ushort*)&h;
}

// read 8 contiguous bf16 from LDS as two 8B chunks (8B-aligned offsets only)
__device__ __forceinline__ s16x8 lds_frag(const ushort* p) {
    s16x4v lo = *(const s16x4v*)p;
    s16x4v hi = *(const s16x4v*)(p + 4);
    return __builtin_shufflevector(lo, hi, 0, 1, 2, 3, 4, 5, 6, 7);
}

// 16B-aligned LDS fragment read (GEMM k-slots are row*128B + slot*16B)
__device__ __forceinline__ s16x8 lds_frag16(const ushort* p) {
    return *(const s16x8*)p;
}

// ---------------------------------------------------------------------------
// One weight-prep tile (canonical id 0..1736 for one layer):
//   0..431   QKV transpose (3 x 144 tiles of 768x768)
//   432..575 O transpose
//   576..1151 W1 transpose (768x3072)
//   1152..1727 W2 transpose (3072x768)
//   1728..1736 bias concat
// fp32 [K][N] -> bf16 TILED [N/64][K/64][64][64] (contiguous 8KB per tile).
// Runs with 256 threads; needs a 64x68 float LDS tile.
// ---------------------------------------------------------------------------
__device__ __forceinline__ void prep_tile_body(
    int id, int l,
    const float* __restrict__ Wq, const float* __restrict__ Wk,
    const float* __restrict__ Wv, const float* __restrict__ Wo,
    const float* __restrict__ W1, const float* __restrict__ W2,
    const float* __restrict__ bq, const float* __restrict__ bk,
    const float* __restrict__ bv,
    ushort* __restrict__ Wt_qkv, ushort* __restrict__ Wt_o,
    ushort* __restrict__ Wt_1, ushort* __restrict__ Wt_2,
    float* __restrict__ b_qkv, float (*tile)[68])
{
    const int tid = threadIdx.x;

    if (id >= 1728) {                  // bias concat: 9 blocks x 256
        int i = (id - 1728) * 256 + tid;
        if (i < QKVN)
            b_qkv[(size_t)l * QKVN + i] =
                (i < H_) ? bq[l * H_ + i]
                         : ((i < 2 * H_) ? bk[l * H_ + i - H_] : bv[l * H_ + i - 2 * H_]);
        return;
    }

    const float* src; ushort* dst; int N, ncols, ktiles, t;
    if (id < 432) {                    // QKV: 3 mats x 144 tiles of 768x768
        const int mat = id / 144; t = id % 144;
        src = (mat == 0) ? (Wq + (size_t)l * H_ * H_)
            : (mat == 1) ? (Wk + (size_t)l * H_ * H_)
                         : (Wv + (size_t)l * H_ * H_);
        dst = Wt_qkv + (size_t)l * 3 * H_ * H_ + (size_t)mat * H_ * H_;
        N = H_; ncols = 12; ktiles = 12;
    } else if (id < 576) {             // O: 144 tiles
        t = id - 432;
        src = Wo + (size_t)l * H_ * H_;
        dst = Wt_o + (size_t)l * H_ * H_;
        N = H_; ncols = 12; ktiles = 12;
    } else if (id < 1152) {            // W1: 768x3072, 576 tiles
        t = id - 576;
        src = W1 + (size_t)l * H_ * FF_;
        dst = Wt_1 + (size_t)l * H_ * FF_;
        N = FF_; ncols = 48; ktiles = 12;
    } else {                           // W2: 3072x768, 576 tiles
        t = id - 1152;
        src = W2 + (size_t)l * FF_ * H_;
        dst = Wt_2 + (size_t)l * FF_ * H_;
        N = H_; ncols = 12; ktiles = 48;
    }

    const int n0 = (t % ncols) * 64;
    const int k0 = (t / ncols) * 64;

    // load: 64 rows x 64 floats, float4 per lane (16 lanes = 256B per row)
    const int lr = tid >> 4;           // 0..15
    const int lc = tid & 15;           // 0..15
#pragma unroll
    for (int i = 0; i < 4; i++)
        *(f32x4*)&tile[lr + 16 * i][lc * 4] =
            *(const f32x4*)&src[(size_t)(k0 + lr + 16 * i) * N + n0 + lc * 4];
    __syncthreads();

    // store: ONE contiguous 8KB tile, thread tid writes bytes [32*tid,32*tid+32)
    const int rn = tid >> 2;           // 0..63
    const int kc = tid & 3;            // 0..3 (16 k each)
    s16x8 o0, o1;
#pragma unroll
    for (int j = 0; j < 8; j++) o0[j] = (short)f2bu(tile[kc * 16 + j][rn]);
#pragma unroll
    for (int j = 0; j < 8; j++) o1[j] = (short)f2bu(tile[kc * 16 + 8 + j][rn]);
    ushort* dp = dst + ((size_t)(n0 >> 6) * ktiles + (k0 >> 6)) * 4096 + tid * 16;
    *(s16x8*)dp       = o0;
    *(s16x8*)(dp + 8) = o1;
}

// aux plane dispatcher for host kernels.
// mode 0: QKV tiles + bias  (t: 0..440  -> canon 0..431, 1728..1736)
// mode 1: O + W1            (t: 0..719  -> canon 432..1151)
// mode 2: W2                (t: 0..575  -> canon 1152..1727)
__device__ __forceinline__ void prep_aux(
    int mode, int t, int l,
    const float* Wq, const float* Wk, const float* Wv, const float* Wo,
    const float* W1, const float* W2,
    const float* bq, const float* bk, const float* bv,
    ushort* Wt_qkv, ushort* Wt_o, ushort* Wt_1, ushort* Wt_2,
    float* b_qkv, float (*tile)[68])
{
    int canon;
    if (mode == 0) {
        if (t >= 441) return;
        canon = (t < 432) ? t : 1728 + (t - 432);
    } else if (mode == 1) {
        if (t >= 720) return;
        canon = 432 + t;
    } else {
        if (t >= 576) return;
        canon = 1152 + t;
    }
    prep_tile_body(canon, l, Wq, Wk, Wv, Wo, W1, W2, bq, bk, bv,
                   Wt_qkv, Wt_o, Wt_1, Wt_2, b_qkv, tile);
}

// ---------------------------------------------------------------------------
// Embedding gather + LayerNorm body (y==1 plane of prep_embed).
// ---------------------------------------------------------------------------
__device__ __forceinline__ void embed_body(
    const int* __restrict__ ids, const int* __restrict__ tt,
    const float* __restrict__ wemb, const float* __restrict__ pemb,
    const float* __restrict__ temb, const float* __restrict__ g,
    const float* __restrict__ bb, float* __restrict__ x,
    __hip_bfloat16* __restrict__ xb, float* red)
{
    const int t = blockIdx.x;
    const int s = t % S_;
    const int tid = threadIdx.x;

    const float* wr = wemb + (size_t)ids[t] * H_;
    const float* pr = pemb + (size_t)s * H_;
    const float* tr = temb + (size_t)tt[t] * H_;

    float v[3];
    float sum = 0.f;
#pragma unroll
    for (int i = 0; i < 3; i++) {
        int c = tid + i * 256;
        v[i] = wr[c] + pr[c] + tr[c];
        sum += v[i];
    }
    red[tid] = sum; __syncthreads();
    for (int st = 128; st > 0; st >>= 1) { if (tid < st) red[tid] += red[tid + st]; __syncthreads(); }
    const float mean = red[0] / (float)H_;
    __syncthreads();
    float s2 = 0.f;
#pragma unroll
    for (int i = 0; i < 3; i++) { float d = v[i] - mean; s2 += d * d; }
    red[tid] = s2; __syncthreads();
    for (int st = 128; st > 0; st >>= 1) { if (tid < st) red[tid] += red[tid + st]; __syncthreads(); }
    const float rstd = rsqrtf(red[0] / (float)H_ + 1e-12f);
#pragma unroll
    for (int i = 0; i < 3; i++) {
        int c = tid + i * 256;
        float o = (v[i] - mean) * rstd * g[c] + bb[c];
        x[(size_t)t * H_ + c] = o;
        xb[(size_t)t * H_ + c] = __float2bfloat16(o);
    }
}

// ---------------------------------------------------------------------------
// Initial launch: layer-0 weight prep (y==0) + embedding (y==1).
// Layers 1..5 prep is hosted inside the layer-l QKV/attn/FF1 launches.
// ---------------------------------------------------------------------------
__global__ __launch_bounds__(256) void prep_embed_kernel(
    const float* __restrict__ Wq, const float* __restrict__ Wk,
    const float* __restrict__ Wv, const float* __restrict__ Wo,
    const float* __restrict__ W1, const float* __restrict__ W2,
    const float* __restrict__ bq, const float* __restrict__ bk,
    const float* __restrict__ bv,
    ushort* __restrict__ Wt_qkv, ushort* __restrict__ Wt_o,
    ushort* __restrict__ Wt_1, ushort* __restrict__ Wt_2,
    float* __restrict__ b_qkv,
    const int* __restrict__ ids, const int* __restrict__ tt,
    const float* __restrict__ wemb, const float* __restrict__ pemb,
    const float* __restrict__ temb, const float* __restrict__ eg,
    const float* __restrict__ eb, float* __restrict__ x,
    __hip_bfloat16* __restrict__ xb)
{
    __shared__ __align__(16) float tile[64][68];

    if (blockIdx.y == 1) {
        embed_body(ids, tt, wemb, pemb, temb, eg, eb, x, xb, (float*)tile);
        return;
    }
    const int id = blockIdx.x;
    if (id < 1737)
        prep_tile_body(id, 0, Wq, Wk, Wv, Wo, W1, W2, bq, bk, bv,
                       Wt_qkv, Wt_o, Wt_1, Wt_2, b_qkv, tile);
}

// ---------------------------------------------------------------------------
// bf16 MFMA GEMM: C[M][N] = A[M][K] @ B^T + bias, B stored TILED
// [n/64][k/64][64][64].  128x128 tile, BK=64, double-buffered LDS,
// XOR-swizzled k-slots.  blocks with blockIdx.x >= N/TN are AUX prep planes
// (next-layer weight transpose), overlapping the GEMM.
// NS = K-split count.  EPI: 1=exact gelu.  OUTBF: bf16 out.
// ---------------------------------------------------------------------------
#define TM 128
#define TN 128
#define TK 64

template<int EPI, int OUTBF, int NS>
__global__ __launch_bounds__(256) void gemm_mfma_kernel(
    const ushort* __restrict__ A, const ushort* __restrict__ Bt,
    const float* __restrict__ bias, void* __restrict__ Cout,
    int M, int K, int N,
    int auxMode, int lnext,
    const float* Wq, const float* Wk, const float* Wv, const float* Wo,
    const float* W1, const float* W2,
    const float* bq, const float* bk, const float* bv,
    ushort* Wt_qkv, ushort* Wt_o, ushort* Wt_1, ushort* Wt_2,
    float* b_qkv)
{
    __shared__ alignas(16) ushort As[2][TM * TK];
    __shared__ alignas(16) ushort Bs[2][TN * TK];

    const int NX = N / TN;
    if ((int)blockIdx.x >= NX) {       // aux prep plane
        if (auxMode >= 0 && blockIdx.z == 0) {
            const int t = ((int)blockIdx.x - NX) * gridDim.y + blockIdx.y;
            prep_aux(auxMode, t, lnext, Wq, Wk, Wv, Wo, W1, W2, bq, bk, bv,
                     Wt_qkv, Wt_o, Wt_1, Wt_2, b_qkv, (float(*)[68])As);
        }
        return;
    }

    const int tid  = threadIdx.x;
    const int lane = tid & 63;
    const int wave = tid >> 6;
    const int m0 = blockIdx.y * TM;
    const int n0 = blockIdx.x * TN;
    const int wm = (wave >> 1) * 64;
    const int wn = (wave & 1) * 64;

    const int Ksub = K / NS;
    const int Kt   = K >> 6;              // k-tiles in tiled B layout
    int kt0 = 0;
    if (NS > 1) {                         // K-split offsets
        A  += (size_t)blockIdx.z * Ksub;  // A row-major
        kt0 = blockIdx.z * (Ksub >> 6);   // B tiled
    }

    f32x4 acc[4][4];
#pragma unroll
    for (int i = 0; i < 4; i++)
#pragma unroll
        for (int j = 0; j < 4; j++)
            acc[i][j] = (f32x4){0.f, 0.f, 0.f, 0.f};

    // staging: wave stages rows [wave*32, wave*32+32) of A and B as 4 chunks
    // of 8 rows (1KB).  lane -> row r8=lane>>3, slot sl=lane&7; slot sl of
    // row r holds k-group sl^(r&7).
    const int r8 = lane >> 3;
    const int sl = lane & 7;
    const int gk = (sl ^ r8) * 8;
    const ushort* aSrc[4];
    const ushort* bSrc[4];                 // tiled: advance 4096 elems per K-step
    int dOff[4];
#pragma unroll
    for (int c = 0; c < 4; c++) {
        const int R = wave * 32 + c * 8;
        aSrc[c] = A + (size_t)(m0 + R + r8) * K + gk;
        const int n = n0 + R + r8;
        bSrc[c] = Bt + ((size_t)(n >> 6) * Kt + kt0) * 4096 + (n & 63) * 64 + gk;
        dOff[c] = R * TK;
    }

    const int fr = lane & 15;
    const int q4 = lane >> 4;
    int offA[4][2], offB[4][2];
#pragma unroll
    for (int i = 0; i < 4; i++) {
        const int rowA = wm + i * 16 + fr;
        const int rowB = wn + i * 16 + fr;
#pragma unroll
        for (int ks = 0; ks < 2; ks++) {
            offA[i][ks] = rowA * TK + (((ks * 4 + q4) ^ (rowA & 7)) * 8);
            offB[i][ks] = rowB * TK + (((ks * 4 + q4) ^ (rowB & 7)) * 8);
        }
    }

    const int niter = Ksub / TK;

#pragma unroll
    for (int c = 0; c < 4; c++) {
        gload_lds16(aSrc[c], &As[0][dOff[c]]);
        gload_lds16(bSrc[c], &Bs[0][dOff[c]]);
    }

    int cur = 0;
    for (int it = 0; it < niter; ++it) {
        __syncthreads();
        if (it + 1 < niter) {
            const int koff = (it + 1) * TK;
            const size_t boff = (size_t)(it + 1) * 4096;
#pragma unroll
            for (int c = 0; c < 4; c++) {
                gload_lds16(aSrc[c] + koff, &As[cur ^ 1][dOff[c]]);
                gload_lds16(bSrc[c] + boff, &Bs[cur ^ 1][dOff[c]]);
            }
        }

#pragma unroll
        for (int ks = 0; ks < 2; ks++) {
            s16x8 af[4], bf[4];
#pragma unroll
            for (int i = 0; i < 4; i++) af[i] = lds_frag16(&As[cur][offA[i][ks]]);
#pragma unroll
            for (int j = 0; j < 4; j++) bf[j] = lds_frag16(&Bs[cur][offB[j][ks]]);
#pragma unroll
            for (int i = 0; i < 4; i++)
#pragma unroll
                for (int j = 0; j < 4; j++)
                    acc[i][j] = __builtin_amdgcn_mfma_f32_16x16x32_bf16(
                        af[i], bf[j], acc[i][j], 0, 0, 0);
        }
        cur ^= 1;
    }

    const int ecol = lane & 15;
    const int erow = (lane >> 4) * 4;
    float* outF = (float*)Cout + (size_t)blockIdx.z * M * N;
#pragma unroll
    for (int j = 0; j < 4; j++) {
        const int gcol = n0 + wn + j * 16 + ecol;
        const float bv = (NS == 1 || blockIdx.z == 0) ? bias[gcol] : 0.f;
#pragma unroll
        for (int i = 0; i < 4; i++) {
#pragma unroll
            for (int r = 0; r < 4; r++) {
                const int grow = m0 + wm + i * 16 + erow + r;
                float v = acc[i][j][r] + bv;
                if (EPI == 1) v = v * 0.5f * (1.0f + erff(v * 0.70710678118654752f));
                if (OUTBF)
                    ((ushort*)Cout)[(size_t)grow * N + gcol] = f2bu(v);
                else
                    outF[(size_t)grow * N + gcol] = v;
            }
        }
    }
}

// ---------------------------------------------------------------------------
// MFMA flash attention; blocks with blockIdx.x >= 8 are AUX prep planes.
// ---------------------------------------------------------------------------
#define VST 68

__global__ __launch_bounds__(256) void flash_attn_mfma_kernel(
    const ushort* __restrict__ QKV, const int* __restrict__ amask,
    __hip_bfloat16* __restrict__ Octx,
    int auxMode, int lnext,
    const float* Wq, const float* Wk, const float* Wv, const float* Wo,
    const float* W1, const float* W2,
    const float* bq, const float* bk, const float* bv,
    ushort* Wt_qkv, ushort* Wt_o, ushort* Wt_1, ushort* Wt_2,
    float* b_qkv)
{
    __shared__ __align__(16) char smem[36864];
    ushort* const Qs  = (ushort*)smem;                 // [64][VST]
    ushort* const Ks  = (ushort*)(smem + 8704);        // [64][VST]
    ushort* const Vt  = (ushort*)(smem + 17408);       // [64][VST]
    ushort* const Ps  = (ushort*)(smem + 26112);       // [4][16][VST]
    float*  const biasS = (float*)(smem + 34816);      // [S_]

    if ((int)blockIdx.x >= S_ / 64) {  // aux prep plane
        if (auxMode >= 0) {
            const int t = ((int)blockIdx.x - S_ / 64) * 48
                        + (int)blockIdx.y * 4 + (int)blockIdx.z;
            prep_aux(auxMode, t, lnext, Wq, Wk, Wv, Wo, W1, W2, bq, bk, bv,
                     Wt_qkv, Wt_o, Wt_1, Wt_2, b_qkv, (float(*)[68])smem);
        }
        return;
    }

    const int q0 = blockIdx.x * 64, h = blockIdx.y, b = blockIdx.z;
    const int tid = threadIdx.x, lane = tid & 63, wave = tid >> 6;

    for (int i = tid; i < S_; i += 256)
        biasS[i] = amask[b * S_ + i] ? 0.f : -1e9f;

    {   // stage Q
        const ushort* qb = QKV + (size_t)(b * S_ + q0) * QKVN + h * DH_;
        const int q = tid >> 2, dg = (tid & 3) * 16;
        s16x8 v0 = *(const s16x8*)(qb + (size_t)q * QKVN + dg);
        s16x8 v1 = *(const s16x8*)(qb + (size_t)q * QKVN + dg + 8);
        ushort* d = &Qs[q * VST + dg];
        *(s16x4v*)(d)      = __builtin_shufflevector(v0, v0, 0, 1, 2, 3);
        *(s16x4v*)(d + 4)  = __builtin_shufflevector(v0, v0, 4, 5, 6, 7);
        *(s16x4v*)(d + 8)  = __builtin_shufflevector(v1, v1, 0, 1, 2, 3);
        *(s16x4v*)(d + 12) = __builtin_shufflevector(v1, v1, 4, 5, 6, 7);
    }
    __syncthreads();

    const int fm = lane & 15;
    const int fk = (lane >> 4) * 8;

    const s16x8 aq0 = lds_frag(&Qs[(wave * 16 + fm) * VST + fk]);
    const s16x8 aq1 = lds_frag(&Qs[(wave * 16 + fm) * VST + 32 + fk]);

    f32x4 acc[4];
#pragma unroll
    for (int j = 0; j < 4; j++) acc[j] = (f32x4){0.f, 0.f, 0.f, 0.f};
    float m_i[4], l_i[4];
#pragma unroll
    for (int r = 0; r < 4; r++) { m_i[r] = -INFINITY; l_i[r] = 0.f; }

    for (int kt = 0; kt < S_; kt += 64) {
        __syncthreads();
        {   // stage K tile [key][d]
            const ushort* kb = QKV + (size_t)(b * S_ + kt) * QKVN + H_ + h * DH_;
            const int ky = tid >> 2, dg = (tid & 3) * 16;
            s16x8 v0 = *(const s16x8*)(kb + (size_t)ky * QKVN + dg);
            s16x8 v1 = *(const s16x8*)(kb + (size_t)ky * QKVN + dg + 8);
            ushort* d = &Ks[ky * VST + dg];
            *(s16x4v*)(d)      = __builtin_shufflevector(v0, v0, 0, 1, 2, 3);
            *(s16x4v*)(d + 4)  = __builtin_shufflevector(v0, v0, 4, 5, 6, 7);
            *(s16x4v*)(d + 8)  = __builtin_shufflevector(v1, v1, 0, 1, 2, 3);
            *(s16x4v*)(d + 12) = __builtin_shufflevector(v1, v1, 4, 5, 6, 7);
        }
        {   // stage V transposed [d][key]
            const ushort* vb = QKV + (size_t)(b * S_ + kt) * QKVN + 2 * H_ + h * DH_;
            const int d = tid & 63, kg = tid >> 6;
#pragma unroll
            for (int kp = 0; kp < 8; kp++) {
                const int key = kg * 16 + kp * 2;
                ushort u0 = vb[(size_t)key * QKVN + d];
                ushort u1 = vb[(size_t)(key + 1) * QKVN + d];
                ushort2 u; u.x = u0; u.y = u1;
                *(ushort2*)&Vt[d * VST + key] = u;
            }
        }
        __syncthreads();

        f32x4 sc[4];
#pragma unroll
        for (int jj = 0; jj < 4; jj++) {
            s16x8 b0 = lds_frag(&Ks[(jj * 16 + fm) * VST + fk]);
            s16x8 b1 = lds_frag(&Ks[(jj * 16 + fm) * VST + 32 + fk]);
            f32x4 z = (f32x4){0.f, 0.f, 0.f, 0.f};
            z = __builtin_amdgcn_mfma_f32_16x16x32_bf16(aq0, b0, z, 0, 0, 0);
            z = __builtin_amdgcn_mfma_f32_16x16x32_bf16(aq1, b1, z, 0, 0, 0);
            sc[jj] = z;
        }

#pragma unroll
        for (int r = 0; r < 4; r++) {
            float mx = -INFINITY;
#pragma unroll
            for (int jj = 0; jj < 4; jj++) {
                float v = sc[jj][r] * 0.125f + biasS[kt + jj * 16 + fm];
                sc[jj][r] = v;
                mx = fmaxf(mx, v);
            }
#pragma unroll
            for (int msk = 1; msk < 16; msk <<= 1) mx = fmaxf(mx, __shfl_xor(mx, msk));
            const float newm = fmaxf(m_i[r], mx);
            const float alpha = __expf(m_i[r] - newm);
            m_i[r] = newm;
            float rs = 0.f;
#pragma unroll
            for (int jj = 0; jj < 4; jj++) {
                float p = __expf(sc[jj][r] - newm);
                sc[jj][r] = p; rs += p;
            }
#pragma unroll
            for (int msk = 1; msk < 16; msk <<= 1) rs += __shfl_xor(rs, msk);
            l_i[r] = l_i[r] * alpha + rs;
#pragma unroll
            for (int jj = 0; jj < 4; jj++) acc[jj][r] *= alpha;
        }

        ushort* const Pw = Ps + wave * 16 * VST;
#pragma unroll
        for (int jj = 0; jj < 4; jj++)
#pragma unroll
            for (int r = 0; r < 4; r++)
                Pw[((lane >> 4) * 4 + r) * VST + jj * 16 + fm] = f2bu(sc[jj][r]);

        const s16x8 ap0 = lds_frag(&Pw[fm * VST + fk]);
        const s16x8 ap1 = lds_frag(&Pw[fm * VST + 32 + fk]);

#pragma unroll
        for (int jj = 0; jj < 4; jj++) {
            s16x8 b0 = lds_frag(&Vt[(jj * 16 + fm) * VST + fk]);
            s16x8 b1 = lds_frag(&Vt[(jj * 16 + fm) * VST + 32 + fk]);
            acc[jj] = __builtin_amdgcn_mfma_f32_16x16x32_bf16(ap0, b0, acc[jj], 0, 0, 0);
            acc[jj] = __builtin_amdgcn_mfma_f32_16x16x32_bf16(ap1, b1, acc[jj], 0, 0, 0);
        }
    }

#pragma unroll
    for (int r = 0; r < 4; r++) {
        const int q = q0 + wave * 16 + (lane >> 4) * 4 + r;
        const float inv = 1.0f / l_i[r];
        __hip_bfloat16* op = Octx + (size_t)(b * S_ + q) * H_ + h * DH_;
#pragma unroll
        for (int jj = 0; jj < 4; jj++)
            op[jj * 16 + fm] = __float2bfloat16(acc[jj][r] * inv);
    }
}

// ---------------------------------------------------------------------------
// x = LN(x + sum of NS delta slabs) in place; writes bf16 shadow xb.
// QA=1: fuse the QA head into the same pass.
// ---------------------------------------------------------------------------
template<int NS, int QA>
__global__ __launch_bounds__(256) void add_ln_kernel(
    float* __restrict__ x, const float* __restrict__ delta,
    const float* __restrict__ g, const float* __restrict__ bb,
    __hip_bfloat16* __restrict__ xb,
    const float* __restrict__ qa_w, const float* __restrict__ qa_b,
    float* __restrict__ em)
{
    const int t = blockIdx.x;
    const int tid = threadIdx.x;
    __shared__ float red[256];
    __shared__ float red2[256];
    const size_t base = (size_t)t * H_;

    float v[3];
    float sum = 0.f;
#pragma unroll
    for (int i = 0; i < 3; i++) {
        int c = tid + i * 256;
        float d = x[base + c];
#pragma unroll
        for (int s = 0; s < NS; s++)
            d += delta[(size_t)s * M_ * H_ + base + c];
        v[i] = d;
        sum += d;
    }
    red[tid] = sum; __syncthreads();
    for (int st = 128; st > 0; st >>= 1) { if (tid < st) red[tid] += red[tid + st]; __syncthreads(); }
    const float mean = red[0] / (float)H_;
    __syncthreads();
    float s2 = 0.f;
#pragma unroll
    for (int i = 0; i < 3; i++) { float d = v[i] - mean; s2 += d * d; }
    red[tid] = s2; __syncthreads();
    for (int st = 128; st > 0; st >>= 1) { if (tid < st) red[tid] += red[tid + st]; __syncthreads(); }
    const float rstd = rsqrtf(red[0] / (float)H_ + 1e-12f);
    float s0 = 0.f, s1 = 0.f;
#pragma unroll
    for (int i = 0; i < 3; i++) {
        int c = tid + i * 256;
        float o = (v[i] - mean) * rstd * g[c] + bb[c];
        x[base + c] = o;
        xb[base + c] = __float2bfloat16(o);
        if (QA) {
            s0 += o * qa_w[c * 2 + 0];
            s1 += o * qa_w[c * 2 + 1];
        }
    }
    if (QA) {
        __syncthreads();
        red[tid] = s0; red2[tid] = s1; __syncthreads();
        for (int st = 128; st > 0; st >>= 1) {
            if (tid < st) { red[tid] += red[tid + st]; red2[tid] += red2[tid + st]; }
            __syncthreads();
        }
        if (tid == 0) {
            em[(size_t)t * 2 + 0] = red[0] + qa_b[0];
            em[(size_t)t * 2 + 1] = red2[0] + qa_b[1];
        }
    }
}

// ---------------------------------------------------------------------------
// CRF via log-semiring parallel reduction (unchanged).
// ---------------------------------------------------------------------------
__device__ __forceinline__ float lse2(float a, float b) {
    float m = fmaxf(a, b);
    return m + log1pf(expf(-fabsf(a - b)));
}

__device__ __forceinline__ float4 lsem_comb(float4 a, float4 b) {
    float4 r;
    r.x = lse2(a.x + b.x, a.y + b.z);
    r.y = lse2(a.x + b.y, a.y + b.w);
    r.z = lse2(a.z + b.x, a.w + b.z);
    r.w = lse2(a.z + b.y, a.w + b.w);
    return r;
}

__global__ __launch_bounds__(256) void crf_parallel_kernel(
    const float* __restrict__ em, const int* __restrict__ amask,
    const int* __restrict__ spos, const int* __restrict__ epos,
    const float* __restrict__ startT, const float* __restrict__ endT,
    const float* __restrict__ trans, float* __restrict__ out)
{
    __shared__ float4 mats[B_][64];
    __shared__ float numred[B_][64];
    __shared__ float cntred[B_][64];
    __shared__ float llh[B_];
    const int tid = threadIdx.x;
    const int s = tid >> 6;
    const int j = tid & 63;
    const float NEG = -1e30f;

    const int sp = spos[s], ep = epos[s];
    const bool valid = (sp >= 0) && (sp < S_) && (ep >= 0) && (ep < S_) && (sp <= ep);
    const float* e = em + (size_t)s * S_ * 2;
    const int* mk = amask + s * S_;
    const float t00 = trans[0], t01 = trans[1], t10 = trans[2], t11 = trans[3];

    float4 C = make_float4(0.f, NEG, NEG, 0.f);
    float num = 0.f, cnt = 0.f;
#pragma unroll
    for (int k = 0; k < 8; k++) {
        const int t = j * 8 + 1 + k;
        float4 Mt = make_float4(0.f, NEG, NEG, 0.f);
        if (t < S_ && mk[t]) {
            const float e0 = e[2 * t], e1 = e[2 * t + 1];
            Mt = make_float4(t00 + e0, t01 + e1, t10 + e0, t11 + e1);
            const int tp = (valid && (t - 1) >= sp && (t - 1) <= ep) ? 1 : 0;
            const int tc = (valid && t >= sp && t <= ep) ? 1 : 0;
            const float tr = tp ? (tc ? t11 : t10) : (tc ? t01 : t00);
            num += tr + (tc ? e1 : e0);
            cnt += 1.f;
        }
        C = (k == 0) ? Mt : lsem_comb(C, Mt);
    }
    if (j == 0) {
        const int tag0 = (valid && 0 >= sp && 0 <= ep) ? 1 : 0;
        num += startT[tag0] + e[tag0];
        cnt += mk[0] ? 1.f : 0.f;
    }
    mats[s][j] = C;
    numred[s][j] = num;
    cntred[s][j] = cnt;
    __syncthreads();

    for (int st = 32; st >= 1; st >>= 1) {
        float4 a, b;
        const bool act = (j < st);
        if (act) { a = mats[s][2 * j]; b = mats[s][2 * j + 1]; }
        __syncthreads();
        if (act) mats[s][j] = lsem_comb(a, b);
        __syncthreads();
    }
    for (int st = 32; st >= 1; st >>= 1) {
        if (j < st) {
            numred[s][j] += numred[s][j + st];
            cntred[s][j] += cntred[s][j + st];
        }
        __syncthreads();
    }

    if (j == 0) {
        float numT = numred[s][0];
        const int last_idx = (int)(cntred[s][0] + 0.5f) - 1;
        const int ltag = (valid && last_idx >= sp && last_idx <= ep) ? 1 : 0;
        numT += endT[ltag];
        const float a00 = startT[0] + e[0];
        const float a01 = startT[1] + e[1];
        const float4 P = mats[s][0];
        const float aF0 = lse2(a00 + P.x, a01 + P.z);
        const float aF1 = lse2(a00 + P.y, a01 + P.w);
        const float logZ = lse2(aF0 + endT[0], aF1 + endT[1]);
        llh[s] = numT - logZ;
    }
    __syncthreads();
    if (tid == 0)
        out[0] = -(llh[0] + llh[1] + llh[2] + llh[3]);
}

// ---------------------------------------------------------------------------
// Launch
// ---------------------------------------------------------------------------
extern "C" void kernel_launch(void* const* d_in, const int* in_sizes, int n_in,
                              void* d_out, int out_size, void* d_ws, size_t ws_size,
                              hipStream_t stream)
{
    const int*   input_ids  = (const int*)  d_in[0];
    const int*   attn_mask  = (const int*)  d_in[1];
    const int*   token_type = (const int*)  d_in[2];
    const int*   start_pos  = (const int*)  d_in[3];
    const int*   end_pos    = (const int*)  d_in[4];
    const float* word_emb   = (const float*)d_in[5];
    const float* pos_emb    = (const float*)d_in[6];
    const float* type_emb   = (const float*)d_in[7];
    const float* emb_ln_g   = (const float*)d_in[8];
    const float* emb_ln_b   = (const float*)d_in[9];
    const float* Wq         = (const float*)d_in[10];
    const float* bq         = (const float*)d_in[11];
    const float* Wk         = (const float*)d_in[12];
    const float* bk         = (const float*)d_in[13];
    const float* Wv         = (const float*)d_in[14];
    const float* bv         = (const float*)d_in[15];
    const float* Wo         = (const float*)d_in[16];
    const float* bo         = (const float*)d_in[17];
    const float* ln1_g      = (const float*)d_in[18];
    const float* ln1_b      = (const float*)d_in[19];
    const float* W1         = (const float*)d_in[20];
    const float* b1         = (const float*)d_in[21];
    const float* W2         = (const float*)d_in[22];
    const float* b2         = (const float*)d_in[23];
    const float* ln2_g      = (const float*)d_in[24];
    const float* ln2_b      = (const float*)d_in[25];
    const float* qa_w       = (const float*)d_in[26];
    const float* qa_b       = (const float*)d_in[27];
    const float* crf_start  = (const float*)d_in[28];
    const float* crf_end    = (const float*)d_in[29];
    const float* crf_trans  = (const float*)d_in[30];
    float* out = (float*)d_out;

    // Workspace carve-up
    float*  x      = (float*)d_ws;                                  // M*H
    float*  tmp768 = x + (size_t)M_ * H_;                           // 4 * M*H (split-K slabs)
    float*  emis   = tmp768 + (size_t)4 * M_ * H_;                  // M*2
    float*  b_qkv  = emis + (size_t)M_ * 2;                         // L*2304
    ushort* xb     = (ushort*)(b_qkv + (size_t)L_ * QKVN);          // M*H
    ushort* qkvb   = xb + (size_t)M_ * H_;                          // M*2304
    ushort* ctxb   = qkvb + (size_t)M_ * QKVN;                      // M*H
    ushort* hb     = ctxb + (size_t)M_ * H_;                        // M*FF
    ushort* Wt_qkv = hb + (size_t)M_ * FF_;                         // L*2304*768 (tiled)
    ushort* Wt_o   = Wt_qkv + (size_t)L_ * QKVN * H_;               // L*768*768  (tiled)
    ushort* Wt_1   = Wt_o + (size_t)L_ * H_ * H_;                   // L*768*3072 (tiled)
    ushort* Wt_2   = Wt_1 + (size_t)L_ * H_ * FF_;                  // L*3072*768 (tiled)

    dim3 blk(256);

    // layer-0 weight prep + embedding
    prep_embed_kernel<<<dim3(2048, 2), blk, 0, stream>>>(
        Wq, Wk, Wv, Wo, W1, W2, bq, bk, bv,
        Wt_qkv, Wt_o, Wt_1, Wt_2, b_qkv,
        input_ids, token_type, word_emb, pos_emb, type_emb,
        emb_ln_g, emb_ln_b, x, (__hip_bfloat16*)xb);

    for (int l = 0; l < L_; l++) {
        const bool host = (l + 1 < L_);   // layers 0..4 host next-layer prep
        const int lnext = l + 1;

        // QKV gemm (+ aux: next QKV tiles + bias; 441 tiles in 28x16 blocks)
        dim3 gQKVl(QKVN / TN + (host ? 28 : 0), M_ / TM);
        gemm_mfma_kernel<0, 1, 1><<<gQKVl, blk, 0, stream>>>(
            xb, Wt_qkv + (size_t)l * QKVN * H_, b_qkv + (size_t)l * QKVN,
            qkvb, M_, H_, QKVN,
            host ? 0 : -1, lnext,
            Wq, Wk, Wv, Wo, W1, W2, bq, bk, bv,
            Wt_qkv, Wt_o, Wt_1, Wt_2, b_qkv);

        // attention (+ aux: next O + W1; 720 tiles in 15x12x4 blocks)
        dim3 gAl(S_ / 64 + (host ? 15 : 0), NH_, B_);
        flash_attn_mfma_kernel<<<gAl, blk, 0, stream>>>(
            qkvb, attn_mask, (__hip_bfloat16*)ctxb,
            host ? 1 : -1, lnext,
            Wq, Wk, Wv, Wo, W1, W2, bq, bk, bv,
            Wt_qkv, Wt_o, Wt_1, Wt_2, b_qkv);

        // O proj, split-K 2
        dim3 gO(H_ / TN, M_ / TM, 2);
        gemm_mfma_kernel<0, 0, 2><<<gO, blk, 0, stream>>>(
            ctxb, Wt_o + (size_t)l * H_ * H_, bo + l * H_, tmp768, M_, H_, H_,
            -1, 0, Wq, Wk, Wv, Wo, W1, W2, bq, bk, bv,
            Wt_qkv, Wt_o, Wt_1, Wt_2, b_qkv);
        add_ln_kernel<2, 0><<<M_, blk, 0, stream>>>(
            x, tmp768, ln1_g + l * H_, ln1_b + l * H_,
            (__hip_bfloat16*)xb, nullptr, nullptr, nullptr);

        // FF1 gemm (+ aux: next W2; 576 tiles in 36x16 blocks)
        dim3 gF1l(FF_ / TN + (host ? 36 : 0), M_ / TM);
        gemm_mfma_kernel<1, 1, 1><<<gF1l, blk, 0, stream>>>(
            xb, Wt_1 + (size_t)l * H_ * FF_, b1 + l * FF_, hb, M_, H_, FF_,
            host ? 2 : -1, lnext,
            Wq, Wk, Wv, Wo, W1, W2, bq, bk, bv,
            Wt_qkv, Wt_o, Wt_1, Wt_2, b_qkv);

        // FF2, split-K 4
        dim3 gF2(H_ / TN, M_ / TM, 4);
        gemm_mfma_kernel<0, 0, 4><<<gF2, blk, 0, stream>>>(
            hb, Wt_2 + (size_t)l * FF_ * H_, b2 + l * H_, tmp768, M_, FF_, H_,
            -1, 0, Wq, Wk, Wv, Wo, W1, W2, bq, bk, bv,
            Wt_qkv, Wt_o, Wt_1, Wt_2, b_qkv);

        if (l == L_ - 1)
            add_ln_kernel<4, 1><<<M_, blk, 0, stream>>>(
                x, tmp768, ln2_g + l * H_, ln2_b + l * H_,
                (__hip_bfloat16*)xb, qa_w, qa_b, emis);
        else
            add_ln_kernel<4, 0><<<M_, blk, 0, stream>>>(
                x, tmp768, ln2_g + l * H_, ln2_b + l * H_,
                (__hip_bfloat16*)xb, nullptr, nullptr, nullptr);
    }

    crf_parallel_kernel<<<1, 256, 0, stream>>>(emis, attn_mask, start_pos, end_pos,
                                               crf_start, crf_end, crf_trans, out);
}

// Round 5
// 1015.620 us; speedup vs baseline: 1.0054x; 1.0054x over previous
//
#include <hip/hip_runtime.h>
#include <hip/hip_bf16.h>
#include <math.h>

// Problem constants
#define B_  4
#define S_  512
#define H_  768
#define NH_ 12
#define DH_ 64
#define FF_ 3072
#define L_  6
#define V_  30522
#define QKVN 2304          // fused QKV output width
#define M_  (B_ * S_)      // 2048 tokens

typedef short s16x8 __attribute__((ext_vector_type(8)));
typedef short s16x4v __attribute__((ext_vector_type(4)));
typedef float f32x4 __attribute__((ext_vector_type(4)));

__device__ __forceinline__ void gload_lds16(const void* g, void* l) {
    __builtin_amdgcn_global_load_lds(
        (const __attribute__((address_space(1))) void*)g,
        (__attribute__((address_space(3))) void*)l,
        16, 0, 0);
}

__device__ __forceinline__ ushort f2bu(float x) {
    __hip_bfloat16 h = __float2bfloat16(x);
    return *(ushort*)&h;
}

// read 8 contiguous bf16 from LDS as two 8B chunks (8B-aligned offsets only)
__device__ __forceinline__ s16x8 lds_frag(const ushort* p) {
    s16x4v lo = *(const s16x4v*)p;
    s16x4v hi = *(const s16x4v*)(p + 4);
    return __builtin_shufflevector(lo, hi, 0, 1, 2, 3, 4, 5, 6, 7);
}

// 16B-aligned LDS fragment read (GEMM k-slots are row*128B + slot*16B)
__device__ __forceinline__ s16x8 lds_frag16(const ushort* p) {
    return *(const s16x8*)p;
}

// ---------------------------------------------------------------------------
// One weight-prep tile (canonical id 0..1736 for one layer):
// fp32 [K][N] -> bf16 TILED [N/64][K/64][64][64] (contiguous 8KB per tile).
// ---------------------------------------------------------------------------
__device__ __forceinline__ void prep_tile_body(
    int id, int l,
    const float* __restrict__ Wq, const float* __restrict__ Wk,
    const float* __restrict__ Wv, const float* __restrict__ Wo,
    const float* __restrict__ W1, const float* __restrict__ W2,
    const float* __restrict__ bq, const float* __restrict__ bk,
    const float* __restrict__ bv,
    ushort* __restrict__ Wt_qkv, ushort* __restrict__ Wt_o,
    ushort* __restrict__ Wt_1, ushort* __restrict__ Wt_2,
    float* __restrict__ b_qkv, float (*tile)[68])
{
    const int tid = threadIdx.x;

    if (id >= 1728) {                  // bias concat: 9 blocks x 256
        int i = (id - 1728) * 256 + tid;
        if (i < QKVN)
            b_qkv[(size_t)l * QKVN + i] =
                (i < H_) ? bq[l * H_ + i]
                         : ((i < 2 * H_) ? bk[l * H_ + i - H_] : bv[l * H_ + i - 2 * H_]);
        return;
    }

    const float* src; ushort* dst; int N, ncols, ktiles, t;
    if (id < 432) {                    // QKV: 3 mats x 144 tiles of 768x768
        const int mat = id / 144; t = id % 144;
        src = (mat == 0) ? (Wq + (size_t)l * H_ * H_)
            : (mat == 1) ? (Wk + (size_t)l * H_ * H_)
                         : (Wv + (size_t)l * H_ * H_);
        dst = Wt_qkv + (size_t)l * 3 * H_ * H_ + (size_t)mat * H_ * H_;
        N = H_; ncols = 12; ktiles = 12;
    } else if (id < 576) {             // O: 144 tiles
        t = id - 432;
        src = Wo + (size_t)l * H_ * H_;
        dst = Wt_o + (size_t)l * H_ * H_;
        N = H_; ncols = 12; ktiles = 12;
    } else if (id < 1152) {            // W1: 768x3072, 576 tiles
        t = id - 576;
        src = W1 + (size_t)l * H_ * FF_;
        dst = Wt_1 + (size_t)l * H_ * FF_;
        N = FF_; ncols = 48; ktiles = 12;
    } else {                           // W2: 3072x768, 576 tiles
        t = id - 1152;
        src = W2 + (size_t)l * FF_ * H_;
        dst = Wt_2 + (size_t)l * FF_ * H_;
        N = H_; ncols = 12; ktiles = 48;
    }

    const int n0 = (t % ncols) * 64;
    const int k0 = (t / ncols) * 64;

    // load: 64 rows x 64 floats, float4 per lane (16 lanes = 256B per row)
    const int lr = tid >> 4;
    const int lc = tid & 15;
#pragma unroll
    for (int i = 0; i < 4; i++)
        *(f32x4*)&tile[lr + 16 * i][lc * 4] =
            *(const f32x4*)&src[(size_t)(k0 + lr + 16 * i) * N + n0 + lc * 4];
    __syncthreads();

    // store: ONE contiguous 8KB tile
    const int rn = tid >> 2;
    const int kc = tid & 3;
    s16x8 o0, o1;
#pragma unroll
    for (int j = 0; j < 8; j++) o0[j] = (short)f2bu(tile[kc * 16 + j][rn]);
#pragma unroll
    for (int j = 0; j < 8; j++) o1[j] = (short)f2bu(tile[kc * 16 + 8 + j][rn]);
    ushort* dp = dst + ((size_t)(n0 >> 6) * ktiles + (k0 >> 6)) * 4096 + tid * 16;
    *(s16x8*)dp       = o0;
    *(s16x8*)(dp + 8) = o1;
}

// ---------------------------------------------------------------------------
// Embedding gather + LayerNorm body (y==L_ plane of prep_embed).
// ---------------------------------------------------------------------------
__device__ __forceinline__ void embed_body(
    const int* __restrict__ ids, const int* __restrict__ tt,
    const float* __restrict__ wemb, const float* __restrict__ pemb,
    const float* __restrict__ temb, const float* __restrict__ g,
    const float* __restrict__ bb, float* __restrict__ x,
    __hip_bfloat16* __restrict__ xb, float* red)
{
    const int t = blockIdx.x;
    const int s = t % S_;
    const int tid = threadIdx.x;

    const float* wr = wemb + (size_t)ids[t] * H_;
    const float* pr = pemb + (size_t)s * H_;
    const float* tr = temb + (size_t)tt[t] * H_;

    float v[3];
    float sum = 0.f;
#pragma unroll
    for (int i = 0; i < 3; i++) {
        int c = tid + i * 256;
        v[i] = wr[c] + pr[c] + tr[c];
        sum += v[i];
    }
    red[tid] = sum; __syncthreads();
    for (int st = 128; st > 0; st >>= 1) { if (tid < st) red[tid] += red[tid + st]; __syncthreads(); }
    const float mean = red[0] / (float)H_;
    __syncthreads();
    float s2 = 0.f;
#pragma unroll
    for (int i = 0; i < 3; i++) { float d = v[i] - mean; s2 += d * d; }
    red[tid] = s2; __syncthreads();
    for (int st = 128; st > 0; st >>= 1) { if (tid < st) red[tid] += red[tid + st]; __syncthreads(); }
    const float rstd = rsqrtf(red[0] / (float)H_ + 1e-12f);
#pragma unroll
    for (int i = 0; i < 3; i++) {
        int c = tid + i * 256;
        float o = (v[i] - mean) * rstd * g[c] + bb[c];
        x[(size_t)t * H_ + c] = o;
        xb[(size_t)t * H_ + c] = __float2bfloat16(o);
    }
}

// ---------------------------------------------------------------------------
// All-layer weight prep (y<L_) + embedding (y==L_), one launch.
// ---------------------------------------------------------------------------
__global__ __launch_bounds__(256) void prep_embed_kernel(
    const float* __restrict__ Wq, const float* __restrict__ Wk,
    const float* __restrict__ Wv, const float* __restrict__ Wo,
    const float* __restrict__ W1, const float* __restrict__ W2,
    const float* __restrict__ bq, const float* __restrict__ bk,
    const float* __restrict__ bv,
    ushort* __restrict__ Wt_qkv, ushort* __restrict__ Wt_o,
    ushort* __restrict__ Wt_1, ushort* __restrict__ Wt_2,
    float* __restrict__ b_qkv,
    const int* __restrict__ ids, const int* __restrict__ tt,
    const float* __restrict__ wemb, const float* __restrict__ pemb,
    const float* __restrict__ temb, const float* __restrict__ eg,
    const float* __restrict__ eb, float* __restrict__ x,
    __hip_bfloat16* __restrict__ xb)
{
    __shared__ __align__(16) float tile[64][68];

    if (blockIdx.y == L_) {
        embed_body(ids, tt, wemb, pemb, temb, eg, eb, x, xb, (float*)tile);
        return;
    }
    const int id = blockIdx.x;
    if (id < 1737)
        prep_tile_body(id, blockIdx.y, Wq, Wk, Wv, Wo, W1, W2, bq, bk, bv,
                       Wt_qkv, Wt_o, Wt_1, Wt_2, b_qkv, tile);
}

// ---------------------------------------------------------------------------
// bf16 MFMA GEMM: C[M][N] = A[M][K] @ B^T + bias, B stored TILED
// [n/64][k/64][64][64].  128x128 tile, BK=64, double-buffered LDS,
// XOR-swizzled k-slots.  NS = K-split count.  EPI 1 = exact gelu.
// ---------------------------------------------------------------------------
#define TM 128
#define TN 128
#define TK 64

template<int EPI, int OUTBF, int NS>
__global__ __launch_bounds__(256) void gemm_mfma_kernel(
    const ushort* __restrict__ A, const ushort* __restrict__ Bt,
    const float* __restrict__ bias, void* __restrict__ Cout,
    int M, int K, int N)
{
    __shared__ alignas(16) ushort As[2][TM * TK];
    __shared__ alignas(16) ushort Bs[2][TN * TK];
    const int tid  = threadIdx.x;
    const int lane = tid & 63;
    const int wave = tid >> 6;
    const int m0 = blockIdx.y * TM;
    const int n0 = blockIdx.x * TN;
    const int wm = (wave >> 1) * 64;
    const int wn = (wave & 1) * 64;

    const int Ksub = K / NS;
    const int Kt   = K >> 6;
    int kt0 = 0;
    if (NS > 1) {
        A  += (size_t)blockIdx.z * Ksub;
        kt0 = blockIdx.z * (Ksub >> 6);
    }

    f32x4 acc[4][4];
#pragma unroll
    for (int i = 0; i < 4; i++)
#pragma unroll
        for (int j = 0; j < 4; j++)
            acc[i][j] = (f32x4){0.f, 0.f, 0.f, 0.f};

    const int r8 = lane >> 3;
    const int sl = lane & 7;
    const int gk = (sl ^ r8) * 8;
    const ushort* aSrc[4];
    const ushort* bSrc[4];
    int dOff[4];
#pragma unroll
    for (int c = 0; c < 4; c++) {
        const int R = wave * 32 + c * 8;
        aSrc[c] = A + (size_t)(m0 + R + r8) * K + gk;
        const int n = n0 + R + r8;
        bSrc[c] = Bt + ((size_t)(n >> 6) * Kt + kt0) * 4096 + (n & 63) * 64 + gk;
        dOff[c] = R * TK;
    }

    const int fr = lane & 15;
    const int q4 = lane >> 4;
    int offA[4][2], offB[4][2];
#pragma unroll
    for (int i = 0; i < 4; i++) {
        const int rowA = wm + i * 16 + fr;
        const int rowB = wn + i * 16 + fr;
#pragma unroll
        for (int ks = 0; ks < 2; ks++) {
            offA[i][ks] = rowA * TK + (((ks * 4 + q4) ^ (rowA & 7)) * 8);
            offB[i][ks] = rowB * TK + (((ks * 4 + q4) ^ (rowB & 7)) * 8);
        }
    }

    const int niter = Ksub / TK;

#pragma unroll
    for (int c = 0; c < 4; c++) {
        gload_lds16(aSrc[c], &As[0][dOff[c]]);
        gload_lds16(bSrc[c], &Bs[0][dOff[c]]);
    }

    int cur = 0;
    for (int it = 0; it < niter; ++it) {
        __syncthreads();
        if (it + 1 < niter) {
            const int koff = (it + 1) * TK;
            const size_t boff = (size_t)(it + 1) * 4096;
#pragma unroll
            for (int c = 0; c < 4; c++) {
                gload_lds16(aSrc[c] + koff, &As[cur ^ 1][dOff[c]]);
                gload_lds16(bSrc[c] + boff, &Bs[cur ^ 1][dOff[c]]);
            }
        }

#pragma unroll
        for (int ks = 0; ks < 2; ks++) {
            s16x8 af[4], bf[4];
#pragma unroll
            for (int i = 0; i < 4; i++) af[i] = lds_frag16(&As[cur][offA[i][ks]]);
#pragma unroll
            for (int j = 0; j < 4; j++) bf[j] = lds_frag16(&Bs[cur][offB[j][ks]]);
#pragma unroll
            for (int i = 0; i < 4; i++)
#pragma unroll
                for (int j = 0; j < 4; j++)
                    acc[i][j] = __builtin_amdgcn_mfma_f32_16x16x32_bf16(
                        af[i], bf[j], acc[i][j], 0, 0, 0);
        }
        cur ^= 1;
    }

    const int ecol = lane & 15;
    const int erow = (lane >> 4) * 4;
    float* outF = (float*)Cout + (size_t)blockIdx.z * M * N;
#pragma unroll
    for (int j = 0; j < 4; j++) {
        const int gcol = n0 + wn + j * 16 + ecol;
        const float bv = (NS == 1 || blockIdx.z == 0) ? bias[gcol] : 0.f;
#pragma unroll
        for (int i = 0; i < 4; i++) {
#pragma unroll
            for (int r = 0; r < 4; r++) {
                const int grow = m0 + wm + i * 16 + erow + r;
                float v = acc[i][j][r] + bv;
                if (EPI == 1) v = v * 0.5f * (1.0f + erff(v * 0.70710678118654752f));
                if (OUTBF)
                    ((ushort*)Cout)[(size_t)grow * N + gcol] = f2bu(v);
                else
                    outF[(size_t)grow * N + gcol] = v;
            }
        }
    }
}

// ---------------------------------------------------------------------------
// MFMA flash attention with register-staged double-buffered K/V (T14):
// per tile: issue next-tile global loads -> compute current -> write regs to
// the other LDS buffer -> ONE barrier.  Global-load latency hides under
// QK/softmax/PV compute instead of being serialized at a staging barrier.
// ---------------------------------------------------------------------------
#define VST 68

__global__ __launch_bounds__(256) void flash_attn_mfma_kernel(
    const ushort* __restrict__ QKV, const int* __restrict__ amask,
    __hip_bfloat16* __restrict__ Octx)
{
    const int q0 = blockIdx.x * 64, h = blockIdx.y, b = blockIdx.z;
    const int tid = threadIdx.x, lane = tid & 63, wave = tid >> 6;
    __shared__ ushort Qs[64 * VST];          // [q][d]
    __shared__ ushort Ks[2][64 * VST];       // [key][d] x2
    __shared__ ushort Vt[2][64 * VST];       // [d][key] x2
    __shared__ ushort Ps[4][16 * VST];       // per-wave [q][key]
    __shared__ float biasS[S_];

    for (int i = tid; i < S_; i += 256)
        biasS[i] = amask[b * S_ + i] ? 0.f : -1e9f;

    // staging index maps
    const int ky = tid >> 2, dg = (tid & 3) * 16;   // K: row ky, d-group dg
    const int dd = tid & 63, kg = tid >> 6;         // V: d=dd, key-group kg

    const ushort* kbase = QKV + (size_t)b * S_ * QKVN + H_ + h * DH_;
    const ushort* vbase = QKV + (size_t)b * S_ * QKVN + 2 * H_ + h * DH_;

    s16x8 kr0, kr1;
    ushort2 vr[8];

#define LOAD_KV(kt)                                                          \
    {                                                                        \
        const ushort* kb = kbase + (size_t)((kt) + ky) * QKVN;               \
        kr0 = *(const s16x8*)(kb + dg);                                      \
        kr1 = *(const s16x8*)(kb + dg + 8);                                  \
        const ushort* vb = vbase + (size_t)(kt) * QKVN + dd;                 \
        _Pragma("unroll")                                                    \
        for (int kp = 0; kp < 8; kp++) {                                     \
            const int key = kg * 16 + kp * 2;                                \
            vr[kp].x = vb[(size_t)key * QKVN];                               \
            vr[kp].y = vb[(size_t)(key + 1) * QKVN];                         \
        }                                                                    \
    }

#define STORE_KV(buf)                                                        \
    {                                                                        \
        ushort* dk = &Ks[buf][ky * VST + dg];                                \
        *(s16x4v*)(dk)      = __builtin_shufflevector(kr0, kr0, 0, 1, 2, 3); \
        *(s16x4v*)(dk + 4)  = __builtin_shufflevector(kr0, kr0, 4, 5, 6, 7); \
        *(s16x4v*)(dk + 8)  = __builtin_shufflevector(kr1, kr1, 0, 1, 2, 3); \
        *(s16x4v*)(dk + 12) = __builtin_shufflevector(kr1, kr1, 4, 5, 6, 7); \
        _Pragma("unroll")                                                    \
        for (int kp = 0; kp < 8; kp++)                                       \
            *(ushort2*)&Vt[buf][dd * VST + kg * 16 + kp * 2] = vr[kp];       \
    }

    {   // stage Q
        const ushort* qb = QKV + (size_t)(b * S_ + q0) * QKVN + h * DH_;
        const int q = tid >> 2;
        s16x8 v0 = *(const s16x8*)(qb + (size_t)q * QKVN + dg);
        s16x8 v1 = *(const s16x8*)(qb + (size_t)q * QKVN + dg + 8);
        ushort* d = &Qs[q * VST + dg];
        *(s16x4v*)(d)      = __builtin_shufflevector(v0, v0, 0, 1, 2, 3);
        *(s16x4v*)(d + 4)  = __builtin_shufflevector(v0, v0, 4, 5, 6, 7);
        *(s16x4v*)(d + 8)  = __builtin_shufflevector(v1, v1, 0, 1, 2, 3);
        *(s16x4v*)(d + 12) = __builtin_shufflevector(v1, v1, 4, 5, 6, 7);
    }
    LOAD_KV(0);
    STORE_KV(0);
    __syncthreads();            // Q + bias + buffer 0 visible

    const int fm = lane & 15;
    const int fk = (lane >> 4) * 8;

    const s16x8 aq0 = lds_frag(&Qs[(wave * 16 + fm) * VST + fk]);
    const s16x8 aq1 = lds_frag(&Qs[(wave * 16 + fm) * VST + 32 + fk]);

    f32x4 acc[4];
#pragma unroll
    for (int j = 0; j < 4; j++) acc[j] = (f32x4){0.f, 0.f, 0.f, 0.f};
    float m_i[4], l_i[4];
#pragma unroll
    for (int r = 0; r < 4; r++) { m_i[r] = -INFINITY; l_i[r] = 0.f; }

    int cur = 0;
    for (int ti = 0; ti < S_ / 64; ti++) {
        const int kt = ti * 64;
        if (ti + 1 < S_ / 64) LOAD_KV(kt + 64);   // in flight during compute

        const ushort* Ksc = Ks[cur];
        const ushort* Vtc = Vt[cur];

        f32x4 sc[4];
        __builtin_amdgcn_s_setprio(1);
#pragma unroll
        for (int jj = 0; jj < 4; jj++) {
            s16x8 b0 = lds_frag(&Ksc[(jj * 16 + fm) * VST + fk]);
            s16x8 b1 = lds_frag(&Ksc[(jj * 16 + fm) * VST + 32 + fk]);
            f32x4 z = (f32x4){0.f, 0.f, 0.f, 0.f};
            z = __builtin_amdgcn_mfma_f32_16x16x32_bf16(aq0, b0, z, 0, 0, 0);
            z = __builtin_amdgcn_mfma_f32_16x16x32_bf16(aq1, b1, z, 0, 0, 0);
            sc[jj] = z;
        }
        __builtin_amdgcn_s_setprio(0);

#pragma unroll
        for (int r = 0; r < 4; r++) {
            float mx = -INFINITY;
#pragma unroll
            for (int jj = 0; jj < 4; jj++) {
                float v = sc[jj][r] * 0.125f + biasS[kt + jj * 16 + fm];
                sc[jj][r] = v;
                mx = fmaxf(mx, v);
            }
#pragma unroll
            for (int msk = 1; msk < 16; msk <<= 1) mx = fmaxf(mx, __shfl_xor(mx, msk));
            const float newm = fmaxf(m_i[r], mx);
            const float alpha = __expf(m_i[r] - newm);
            m_i[r] = newm;
            float rs = 0.f;
#pragma unroll
            for (int jj = 0; jj < 4; jj++) {
                float p = __expf(sc[jj][r] - newm);
                sc[jj][r] = p; rs += p;
            }
#pragma unroll
            for (int msk = 1; msk < 16; msk <<= 1) rs += __shfl_xor(rs, msk);
            l_i[r] = l_i[r] * alpha + rs;
#pragma unroll
            for (int jj = 0; jj < 4; jj++) acc[jj][r] *= alpha;
        }

        ushort* const Pw = &Ps[wave][0];
#pragma unroll
        for (int jj = 0; jj < 4; jj++)
#pragma unroll
            for (int r = 0; r < 4; r++)
                Pw[((lane >> 4) * 4 + r) * VST + jj * 16 + fm] = f2bu(sc[jj][r]);

        const s16x8 ap0 = lds_frag(&Pw[fm * VST + fk]);
        const s16x8 ap1 = lds_frag(&Pw[fm * VST + 32 + fk]);

        __builtin_amdgcn_s_setprio(1);
#pragma unroll
        for (int jj = 0; jj < 4; jj++) {
            s16x8 b0 = lds_frag(&Vtc[(jj * 16 + fm) * VST + fk]);
            s16x8 b1 = lds_frag(&Vtc[(jj * 16 + fm) * VST + 32 + fk]);
            acc[jj] = __builtin_amdgcn_mfma_f32_16x16x32_bf16(ap0, b0, acc[jj], 0, 0, 0);
            acc[jj] = __builtin_amdgcn_mfma_f32_16x16x32_bf16(ap1, b1, acc[jj], 0, 0, 0);
        }
        __builtin_amdgcn_s_setprio(0);

        if (ti + 1 < S_ / 64) {
            STORE_KV(cur ^ 1);   // cur^1 last read at tile ti-1; barrier at end
            __syncthreads();     // of ti-1 guarantees safety; this one publishes
        }
        cur ^= 1;
    }
#undef LOAD_KV
#undef STORE_KV

#pragma unroll
    for (int r = 0; r < 4; r++) {
        const int q = q0 + wave * 16 + (lane >> 4) * 4 + r;
        const float inv = 1.0f / l_i[r];
        __hip_bfloat16* op = Octx + (size_t)(b * S_ + q) * H_ + h * DH_;
#pragma unroll
        for (int jj = 0; jj < 4; jj++)
            op[jj * 16 + fm] = __float2bfloat16(acc[jj][r] * inv);
    }
}

// ---------------------------------------------------------------------------
// x = LN(x + sum of NS delta slabs) in place; writes bf16 shadow xb.
// QA=1: fuse the QA head into the same pass.
// ---------------------------------------------------------------------------
template<int NS, int QA>
__global__ __launch_bounds__(256) void add_ln_kernel(
    float* __restrict__ x, const float* __restrict__ delta,
    const float* __restrict__ g, const float* __restrict__ bb,
    __hip_bfloat16* __restrict__ xb,
    const float* __restrict__ qa_w, const float* __restrict__ qa_b,
    float* __restrict__ em)
{
    const int t = blockIdx.x;
    const int tid = threadIdx.x;
    __shared__ float red[256];
    __shared__ float red2[256];
    const size_t base = (size_t)t * H_;

    float v[3];
    float sum = 0.f;
#pragma unroll
    for (int i = 0; i < 3; i++) {
        int c = tid + i * 256;
        float d = x[base + c];
#pragma unroll
        for (int s = 0; s < NS; s++)
            d += delta[(size_t)s * M_ * H_ + base + c];
        v[i] = d;
        sum += d;
    }
    red[tid] = sum; __syncthreads();
    for (int st = 128; st > 0; st >>= 1) { if (tid < st) red[tid] += red[tid + st]; __syncthreads(); }
    const float mean = red[0] / (float)H_;
    __syncthreads();
    float s2 = 0.f;
#pragma unroll
    for (int i = 0; i < 3; i++) { float d = v[i] - mean; s2 += d * d; }
    red[tid] = s2; __syncthreads();
    for (int st = 128; st > 0; st >>= 1) { if (tid < st) red[tid] += red[tid + st]; __syncthreads(); }
    const float rstd = rsqrtf(red[0] / (float)H_ + 1e-12f);
    float s0 = 0.f, s1 = 0.f;
#pragma unroll
    for (int i = 0; i < 3; i++) {
        int c = tid + i * 256;
        float o = (v[i] - mean) * rstd * g[c] + bb[c];
        x[base + c] = o;
        xb[base + c] = __float2bfloat16(o);
        if (QA) {
            s0 += o * qa_w[c * 2 + 0];
            s1 += o * qa_w[c * 2 + 1];
        }
    }
    if (QA) {
        __syncthreads();
        red[tid] = s0; red2[tid] = s1; __syncthreads();
        for (int st = 128; st > 0; st >>= 1) {
            if (tid < st) { red[tid] += red[tid + st]; red2[tid] += red2[tid + st]; }
            __syncthreads();
        }
        if (tid == 0) {
            em[(size_t)t * 2 + 0] = red[0] + qa_b[0];
            em[(size_t)t * 2 + 1] = red2[0] + qa_b[1];
        }
    }
}

// ---------------------------------------------------------------------------
// CRF via log-semiring parallel reduction (unchanged).
// ---------------------------------------------------------------------------
__device__ __forceinline__ float lse2(float a, float b) {
    float m = fmaxf(a, b);
    return m + log1pf(expf(-fabsf(a - b)));
}

__device__ __forceinline__ float4 lsem_comb(float4 a, float4 b) {
    float4 r;
    r.x = lse2(a.x + b.x, a.y + b.z);
    r.y = lse2(a.x + b.y, a.y + b.w);
    r.z = lse2(a.z + b.x, a.w + b.z);
    r.w = lse2(a.z + b.y, a.w + b.w);
    return r;
}

__global__ __launch_bounds__(256) void crf_parallel_kernel(
    const float* __restrict__ em, const int* __restrict__ amask,
    const int* __restrict__ spos, const int* __restrict__ epos,
    const float* __restrict__ startT, const float* __restrict__ endT,
    const float* __restrict__ trans, float* __restrict__ out)
{
    __shared__ float4 mats[B_][64];
    __shared__ float numred[B_][64];
    __shared__ float cntred[B_][64];
    __shared__ float llh[B_];
    const int tid = threadIdx.x;
    const int s = tid >> 6;
    const int j = tid & 63;
    const float NEG = -1e30f;

    const int sp = spos[s], ep = epos[s];
    const bool valid = (sp >= 0) && (sp < S_) && (ep >= 0) && (ep < S_) && (sp <= ep);
    const float* e = em + (size_t)s * S_ * 2;
    const int* mk = amask + s * S_;
    const float t00 = trans[0], t01 = trans[1], t10 = trans[2], t11 = trans[3];

    float4 C = make_float4(0.f, NEG, NEG, 0.f);
    float num = 0.f, cnt = 0.f;
#pragma unroll
    for (int k = 0; k < 8; k++) {
        const int t = j * 8 + 1 + k;
        float4 Mt = make_float4(0.f, NEG, NEG, 0.f);
        if (t < S_ && mk[t]) {
            const float e0 = e[2 * t], e1 = e[2 * t + 1];
            Mt = make_float4(t00 + e0, t01 + e1, t10 + e0, t11 + e1);
            const int tp = (valid && (t - 1) >= sp && (t - 1) <= ep) ? 1 : 0;
            const int tc = (valid && t >= sp && t <= ep) ? 1 : 0;
            const float tr = tp ? (tc ? t11 : t10) : (tc ? t01 : t00);
            num += tr + (tc ? e1 : e0);
            cnt += 1.f;
        }
        C = (k == 0) ? Mt : lsem_comb(C, Mt);
    }
    if (j == 0) {
        const int tag0 = (valid && 0 >= sp && 0 <= ep) ? 1 : 0;
        num += startT[tag0] + e[tag0];
        cnt += mk[0] ? 1.f : 0.f;
    }
    mats[s][j] = C;
    numred[s][j] = num;
    cntred[s][j] = cnt;
    __syncthreads();

    for (int st = 32; st >= 1; st >>= 1) {
        float4 a, b;
        const bool act = (j < st);
        if (act) { a = mats[s][2 * j]; b = mats[s][2 * j + 1]; }
        __syncthreads();
        if (act) mats[s][j] = lsem_comb(a, b);
        __syncthreads();
    }
    for (int st = 32; st >= 1; st >>= 1) {
        if (j < st) {
            numred[s][j] += numred[s][j + st];
            cntred[s][j] += cntred[s][j + st];
        }
        __syncthreads();
    }

    if (j == 0) {
        float numT = numred[s][0];
        const int last_idx = (int)(cntred[s][0] + 0.5f) - 1;
        const int ltag = (valid && last_idx >= sp && last_idx <= ep) ? 1 : 0;
        numT += endT[ltag];
        const float a00 = startT[0] + e[0];
        const float a01 = startT[1] + e[1];
        const float4 P = mats[s][0];
        const float aF0 = lse2(a00 + P.x, a01 + P.z);
        const float aF1 = lse2(a00 + P.y, a01 + P.w);
        const float logZ = lse2(aF0 + endT[0], aF1 + endT[1]);
        llh[s] = numT - logZ;
    }
    __syncthreads();
    if (tid == 0)
        out[0] = -(llh[0] + llh[1] + llh[2] + llh[3]);
}

// ---------------------------------------------------------------------------
// Launch
// ---------------------------------------------------------------------------
extern "C" void kernel_launch(void* const* d_in, const int* in_sizes, int n_in,
                              void* d_out, int out_size, void* d_ws, size_t ws_size,
                              hipStream_t stream)
{
    const int*   input_ids  = (const int*)  d_in[0];
    const int*   attn_mask  = (const int*)  d_in[1];
    const int*   token_type = (const int*)  d_in[2];
    const int*   start_pos  = (const int*)  d_in[3];
    const int*   end_pos    = (const int*)  d_in[4];
    const float* word_emb   = (const float*)d_in[5];
    const float* pos_emb    = (const float*)d_in[6];
    const float* type_emb   = (const float*)d_in[7];
    const float* emb_ln_g   = (const float*)d_in[8];
    const float* emb_ln_b   = (const float*)d_in[9];
    const float* Wq         = (const float*)d_in[10];
    const float* bq         = (const float*)d_in[11];
    const float* Wk         = (const float*)d_in[12];
    const float* bk         = (const float*)d_in[13];
    const float* Wv         = (const float*)d_in[14];
    const float* bv         = (const float*)d_in[15];
    const float* Wo         = (const float*)d_in[16];
    const float* bo         = (const float*)d_in[17];
    const float* ln1_g      = (const float*)d_in[18];
    const float* ln1_b      = (const float*)d_in[19];
    const float* W1         = (const float*)d_in[20];
    const float* b1         = (const float*)d_in[21];
    const float* W2         = (const float*)d_in[22];
    const float* b2         = (const float*)d_in[23];
    const float* ln2_g      = (const float*)d_in[24];
    const float* ln2_b      = (const float*)d_in[25];
    const float* qa_w       = (const float*)d_in[26];
    const float* qa_b       = (const float*)d_in[27];
    const float* crf_start  = (const float*)d_in[28];
    const float* crf_end    = (const float*)d_in[29];
    const float* crf_trans  = (const float*)d_in[30];
    float* out = (float*)d_out;

    // Workspace carve-up
    float*  x      = (float*)d_ws;                                  // M*H
    float*  tmp768 = x + (size_t)M_ * H_;                           // 4 * M*H (split-K slabs)
    float*  emis   = tmp768 + (size_t)4 * M_ * H_;                  // M*2
    float*  b_qkv  = emis + (size_t)M_ * 2;                         // L*2304
    ushort* xb     = (ushort*)(b_qkv + (size_t)L_ * QKVN);          // M*H
    ushort* qkvb   = xb + (size_t)M_ * H_;                          // M*2304
    ushort* ctxb   = qkvb + (size_t)M_ * QKVN;                      // M*H
    ushort* hb     = ctxb + (size_t)M_ * H_;                        // M*FF
    ushort* Wt_qkv = hb + (size_t)M_ * FF_;                         // L*2304*768 (tiled)
    ushort* Wt_o   = Wt_qkv + (size_t)L_ * QKVN * H_;               // L*768*768  (tiled)
    ushort* Wt_1   = Wt_o + (size_t)L_ * H_ * H_;                   // L*768*3072 (tiled)
    ushort* Wt_2   = Wt_1 + (size_t)L_ * H_ * FF_;                  // L*3072*768 (tiled)

    dim3 blk(256);

    // all-layer weight prep + embedding in one launch
    prep_embed_kernel<<<dim3(2048, L_ + 1), blk, 0, stream>>>(
        Wq, Wk, Wv, Wo, W1, W2, bq, bk, bv,
        Wt_qkv, Wt_o, Wt_1, Wt_2, b_qkv,
        input_ids, token_type, word_emb, pos_emb, type_emb,
        emb_ln_g, emb_ln_b, x, (__hip_bfloat16*)xb);

    const dim3 gQKV(QKVN / TN, M_ / TM);      // 18 x 16
    const dim3 gO(H_ / TN, M_ / TM, 2);       //  6 x 16 x 2 (split-K)
    const dim3 gF1(FF_ / TN, M_ / TM);        // 24 x 16
    const dim3 gF2(H_ / TN, M_ / TM, 4);      //  6 x 16 x 4 (split-K)
    const dim3 gA(S_ / 64, NH_, B_);          //  8 x 12 x 4

    for (int l = 0; l < L_; l++) {
        gemm_mfma_kernel<0, 1, 1><<<gQKV, blk, 0, stream>>>(
            xb, Wt_qkv + (size_t)l * QKVN * H_, b_qkv + (size_t)l * QKVN,
            qkvb, M_, H_, QKVN);

        flash_attn_mfma_kernel<<<gA, blk, 0, stream>>>(
            qkvb, attn_mask, (__hip_bfloat16*)ctxb);

        gemm_mfma_kernel<0, 0, 2><<<gO, blk, 0, stream>>>(
            ctxb, Wt_o + (size_t)l * H_ * H_, bo + l * H_, tmp768, M_, H_, H_);
        add_ln_kernel<2, 0><<<M_, blk, 0, stream>>>(
            x, tmp768, ln1_g + l * H_, ln1_b + l * H_,
            (__hip_bfloat16*)xb, nullptr, nullptr, nullptr);

        gemm_mfma_kernel<1, 1, 1><<<gF1, blk, 0, stream>>>(
            xb, Wt_1 + (size_t)l * H_ * FF_, b1 + l * FF_, hb, M_, H_, FF_);
        gemm_mfma_kernel<0, 0, 4><<<gF2, blk, 0, stream>>>(
            hb, Wt_2 + (size_t)l * FF_ * H_, b2 + l * H_, tmp768, M_, FF_, H_);
        if (l == L_ - 1)
            add_ln_kernel<4, 1><<<M_, blk, 0, stream>>>(
                x, tmp768, ln2_g + l * H_, ln2_b + l * H_,
                (__hip_bfloat16*)xb, qa_w, qa_b, emis);
        else
            add_ln_kernel<4, 0><<<M_, blk, 0, stream>>>(
                x, tmp768, ln2_g + l * H_, ln2_b + l * H_,
                (__hip_bfloat16*)xb, nullptr, nullptr, nullptr);
    }

    crf_parallel_kernel<<<1, 256, 0, stream>>>(emis, attn_mask, start_pos, end_pos,
                                               crf_start, crf_end, crf_trans, out);
}

// Round 6
// 941.639 us; speedup vs baseline: 1.0844x; 1.0786x over previous
//
#include <hip/hip_runtime.h>
#include <hip/hip_bf16.h>
#include <math.h>

// Problem constants
#define B_  4
#define S_  512
#define H_  768
#define NH_ 12
#define DH_ 64
#define FF_ 3072
#define L_  6
#define V_  30522
#define QKVN 2304          // fused QKV output width
#define M_  (B_ * S_)      // 2048 tokens

typedef short s16x8 __attribute__((ext_vector_type(8)));
typedef short s16x4v __attribute__((ext_vector_type(4)));
typedef float f32x4 __attribute__((ext_vector_type(4)));

__device__ __forceinline__ void gload_lds16(const void* g, void* l) {
    __builtin_amdgcn_global_load_lds(
        (const __attribute__((address_space(1))) void*)g,
        (__attribute__((address_space(3))) void*)l,
        16, 0, 0);
}

__device__ __forceinline__ ushort f2bu(float x) {
    __hip_bfloat16 h = __float2bfloat16(x);
    return *(ushort*)&h;
}

// read 8 contiguous bf16 from LDS as two 8B chunks (8B-aligned offsets only)
__device__ __forceinline__ s16x8 lds_frag(const ushort* p) {
    s16x4v lo = *(const s16x4v*)p;
    s16x4v hi = *(const s16x4v*)(p + 4);
    return __builtin_shufflevector(lo, hi, 0, 1, 2, 3, 4, 5, 6, 7);
}

// 16B-aligned LDS fragment read (GEMM k-slots are row*128B + slot*16B)
__device__ __forceinline__ s16x8 lds_frag16(const ushort* p) {
    return *(const s16x8*)p;
}

// ---------------------------------------------------------------------------
// One weight-prep tile (canonical id 0..1736 for one layer):
// fp32 [K][N] -> bf16 TILED [N/64][K/64][64][64] (contiguous 8KB per tile).
// ---------------------------------------------------------------------------
__device__ __forceinline__ void prep_tile_body(
    int id, int l,
    const float* __restrict__ Wq, const float* __restrict__ Wk,
    const float* __restrict__ Wv, const float* __restrict__ Wo,
    const float* __restrict__ W1, const float* __restrict__ W2,
    const float* __restrict__ bq, const float* __restrict__ bk,
    const float* __restrict__ bv,
    ushort* __restrict__ Wt_qkv, ushort* __restrict__ Wt_o,
    ushort* __restrict__ Wt_1, ushort* __restrict__ Wt_2,
    float* __restrict__ b_qkv, float (*tile)[68])
{
    const int tid = threadIdx.x;

    if (id >= 1728) {                  // bias concat: 9 blocks x 256
        int i = (id - 1728) * 256 + tid;
        if (i < QKVN)
            b_qkv[(size_t)l * QKVN + i] =
                (i < H_) ? bq[l * H_ + i]
                         : ((i < 2 * H_) ? bk[l * H_ + i - H_] : bv[l * H_ + i - 2 * H_]);
        return;
    }

    const float* src; ushort* dst; int N, ncols, ktiles, t;
    if (id < 432) {                    // QKV: 3 mats x 144 tiles of 768x768
        const int mat = id / 144; t = id % 144;
        src = (mat == 0) ? (Wq + (size_t)l * H_ * H_)
            : (mat == 1) ? (Wk + (size_t)l * H_ * H_)
                         : (Wv + (size_t)l * H_ * H_);
        dst = Wt_qkv + (size_t)l * 3 * H_ * H_ + (size_t)mat * H_ * H_;
        N = H_; ncols = 12; ktiles = 12;
    } else if (id < 576) {             // O: 144 tiles
        t = id - 432;
        src = Wo + (size_t)l * H_ * H_;
        dst = Wt_o + (size_t)l * H_ * H_;
        N = H_; ncols = 12; ktiles = 12;
    } else if (id < 1152) {            // W1: 768x3072, 576 tiles
        t = id - 576;
        src = W1 + (size_t)l * H_ * FF_;
        dst = Wt_1 + (size_t)l * H_ * FF_;
        N = FF_; ncols = 48; ktiles = 12;
    } else {                           // W2: 3072x768, 576 tiles
        t = id - 1152;
        src = W2 + (size_t)l * FF_ * H_;
        dst = Wt_2 + (size_t)l * FF_ * H_;
        N = H_; ncols = 12; ktiles = 48;
    }

    const int n0 = (t % ncols) * 64;
    const int k0 = (t / ncols) * 64;

    // load: 64 rows x 64 floats, float4 per lane (16 lanes = 256B per row)
    const int lr = tid >> 4;
    const int lc = tid & 15;
#pragma unroll
    for (int i = 0; i < 4; i++)
        *(f32x4*)&tile[lr + 16 * i][lc * 4] =
            *(const f32x4*)&src[(size_t)(k0 + lr + 16 * i) * N + n0 + lc * 4];
    __syncthreads();

    // store: ONE contiguous 8KB tile
    const int rn = tid >> 2;
    const int kc = tid & 3;
    s16x8 o0, o1;
#pragma unroll
    for (int j = 0; j < 8; j++) o0[j] = (short)f2bu(tile[kc * 16 + j][rn]);
#pragma unroll
    for (int j = 0; j < 8; j++) o1[j] = (short)f2bu(tile[kc * 16 + 8 + j][rn]);
    ushort* dp = dst + ((size_t)(n0 >> 6) * ktiles + (k0 >> 6)) * 4096 + tid * 16;
    *(s16x8*)dp       = o0;
    *(s16x8*)(dp + 8) = o1;
}

// ---------------------------------------------------------------------------
// Embedding gather + LayerNorm body (y==L_ plane of prep_embed).
// ---------------------------------------------------------------------------
__device__ __forceinline__ void embed_body(
    const int* __restrict__ ids, const int* __restrict__ tt,
    const float* __restrict__ wemb, const float* __restrict__ pemb,
    const float* __restrict__ temb, const float* __restrict__ g,
    const float* __restrict__ bb, float* __restrict__ x,
    __hip_bfloat16* __restrict__ xb, float* red)
{
    const int t = blockIdx.x;
    const int s = t % S_;
    const int tid = threadIdx.x;

    const float* wr = wemb + (size_t)ids[t] * H_;
    const float* pr = pemb + (size_t)s * H_;
    const float* tr = temb + (size_t)tt[t] * H_;

    float v[3];
    float sum = 0.f;
#pragma unroll
    for (int i = 0; i < 3; i++) {
        int c = tid + i * 256;
        v[i] = wr[c] + pr[c] + tr[c];
        sum += v[i];
    }
    red[tid] = sum; __syncthreads();
    for (int st = 128; st > 0; st >>= 1) { if (tid < st) red[tid] += red[tid + st]; __syncthreads(); }
    const float mean = red[0] / (float)H_;
    __syncthreads();
    float s2 = 0.f;
#pragma unroll
    for (int i = 0; i < 3; i++) { float d = v[i] - mean; s2 += d * d; }
    red[tid] = s2; __syncthreads();
    for (int st = 128; st > 0; st >>= 1) { if (tid < st) red[tid] += red[tid + st]; __syncthreads(); }
    const float rstd = rsqrtf(red[0] / (float)H_ + 1e-12f);
#pragma unroll
    for (int i = 0; i < 3; i++) {
        int c = tid + i * 256;
        float o = (v[i] - mean) * rstd * g[c] + bb[c];
        x[(size_t)t * H_ + c] = o;
        xb[(size_t)t * H_ + c] = __float2bfloat16(o);
    }
}

// ---------------------------------------------------------------------------
// All-layer weight prep (y<L_) + embedding (y==L_), one launch.
// ---------------------------------------------------------------------------
__global__ __launch_bounds__(256) void prep_embed_kernel(
    const float* __restrict__ Wq, const float* __restrict__ Wk,
    const float* __restrict__ Wv, const float* __restrict__ Wo,
    const float* __restrict__ W1, const float* __restrict__ W2,
    const float* __restrict__ bq, const float* __restrict__ bk,
    const float* __restrict__ bv,
    ushort* __restrict__ Wt_qkv, ushort* __restrict__ Wt_o,
    ushort* __restrict__ Wt_1, ushort* __restrict__ Wt_2,
    float* __restrict__ b_qkv,
    const int* __restrict__ ids, const int* __restrict__ tt,
    const float* __restrict__ wemb, const float* __restrict__ pemb,
    const float* __restrict__ temb, const float* __restrict__ eg,
    const float* __restrict__ eb, float* __restrict__ x,
    __hip_bfloat16* __restrict__ xb)
{
    __shared__ __align__(16) float tile[64][68];

    if (blockIdx.y == L_) {
        embed_body(ids, tt, wemb, pemb, temb, eg, eb, x, xb, (float*)tile);
        return;
    }
    const int id = blockIdx.x;
    if (id < 1737)
        prep_tile_body(id, blockIdx.y, Wq, Wk, Wv, Wo, W1, W2, bq, bk, bv,
                       Wt_qkv, Wt_o, Wt_1, Wt_2, b_qkv, tile);
}

// ---------------------------------------------------------------------------
// bf16 MFMA GEMM: C[M][N] = A[M][K] @ B^T + bias, B stored TILED
// [n/64][k/64][64][64].  64x128 tile (for occupancy at small M*N grids),
// BK=64, double-buffered LDS (48KB -> 3 blocks/CU), XOR-swizzled k-slots.
// 256 thr = 4 waves (2x2 of 32x64), 16 MFMA/wave/iter.
// NS = K-split count.  EPI 1 = exact gelu.
// ---------------------------------------------------------------------------
#define TM 64
#define TN 128
#define TK 64

template<int EPI, int OUTBF, int NS>
__global__ __launch_bounds__(256) void gemm_mfma_kernel(
    const ushort* __restrict__ A, const ushort* __restrict__ Bt,
    const float* __restrict__ bias, void* __restrict__ Cout,
    int M, int K, int N)
{
    __shared__ alignas(16) ushort As[2][TM * TK];
    __shared__ alignas(16) ushort Bs[2][TN * TK];
    const int tid  = threadIdx.x;
    const int lane = tid & 63;
    const int wave = tid >> 6;
    const int m0 = blockIdx.y * TM;
    const int n0 = blockIdx.x * TN;
    const int wm = (wave >> 1) * 32;
    const int wn = (wave & 1) * 64;

    const int Ksub = K / NS;
    const int Kt   = K >> 6;
    int kt0 = 0;
    if (NS > 1) {
        A  += (size_t)blockIdx.z * Ksub;
        kt0 = blockIdx.z * (Ksub >> 6);
    }

    f32x4 acc[2][4];
#pragma unroll
    for (int i = 0; i < 2; i++)
#pragma unroll
        for (int j = 0; j < 4; j++)
            acc[i][j] = (f32x4){0.f, 0.f, 0.f, 0.f};

    // staging: A 64 rows (wave stages 16 = 2 chunks of 8), B 128 rows (wave
    // stages 32 = 4 chunks of 8).  lane -> row r8=lane>>3, slot sl=lane&7;
    // slot sl of row r holds k-group sl^(r&7); chunk bases are multiples of 8.
    const int r8 = lane >> 3;
    const int sl = lane & 7;
    const int gk = (sl ^ r8) * 8;
    const ushort* aSrc[2];
    const ushort* bSrc[4];
    int dOffA[2], dOffB[4];
#pragma unroll
    for (int c = 0; c < 2; c++) {
        const int R = wave * 16 + c * 8;
        aSrc[c] = A + (size_t)(m0 + R + r8) * K + gk;
        dOffA[c] = R * TK;
    }
#pragma unroll
    for (int c = 0; c < 4; c++) {
        const int R = wave * 32 + c * 8;
        const int n = n0 + R + r8;
        bSrc[c] = Bt + ((size_t)(n >> 6) * Kt + kt0) * 4096 + (n & 63) * 64 + gk;
        dOffB[c] = R * TK;
    }

    const int fr = lane & 15;
    const int q4 = lane >> 4;
    int offA[2][2], offB[4][2];
#pragma unroll
    for (int i = 0; i < 2; i++) {
        const int rowA = wm + i * 16 + fr;
#pragma unroll
        for (int ks = 0; ks < 2; ks++)
            offA[i][ks] = rowA * TK + (((ks * 4 + q4) ^ (rowA & 7)) * 8);
    }
#pragma unroll
    for (int j = 0; j < 4; j++) {
        const int rowB = wn + j * 16 + fr;
#pragma unroll
        for (int ks = 0; ks < 2; ks++)
            offB[j][ks] = rowB * TK + (((ks * 4 + q4) ^ (rowB & 7)) * 8);
    }

    const int niter = Ksub / TK;

#pragma unroll
    for (int c = 0; c < 2; c++) gload_lds16(aSrc[c], &As[0][dOffA[c]]);
#pragma unroll
    for (int c = 0; c < 4; c++) gload_lds16(bSrc[c], &Bs[0][dOffB[c]]);

    int cur = 0;
    for (int it = 0; it < niter; ++it) {
        __syncthreads();
        if (it + 1 < niter) {
            const int koff = (it + 1) * TK;
            const size_t boff = (size_t)(it + 1) * 4096;
#pragma unroll
            for (int c = 0; c < 2; c++)
                gload_lds16(aSrc[c] + koff, &As[cur ^ 1][dOffA[c]]);
#pragma unroll
            for (int c = 0; c < 4; c++)
                gload_lds16(bSrc[c] + boff, &Bs[cur ^ 1][dOffB[c]]);
        }

#pragma unroll
        for (int ks = 0; ks < 2; ks++) {
            s16x8 af[2], bf[4];
#pragma unroll
            for (int i = 0; i < 2; i++) af[i] = lds_frag16(&As[cur][offA[i][ks]]);
#pragma unroll
            for (int j = 0; j < 4; j++) bf[j] = lds_frag16(&Bs[cur][offB[j][ks]]);
#pragma unroll
            for (int i = 0; i < 2; i++)
#pragma unroll
                for (int j = 0; j < 4; j++)
                    acc[i][j] = __builtin_amdgcn_mfma_f32_16x16x32_bf16(
                        af[i], bf[j], acc[i][j], 0, 0, 0);
        }
        cur ^= 1;
    }

    const int ecol = lane & 15;
    const int erow = (lane >> 4) * 4;
    float* outF = (float*)Cout + (size_t)blockIdx.z * M * N;
#pragma unroll
    for (int j = 0; j < 4; j++) {
        const int gcol = n0 + wn + j * 16 + ecol;
        const float bv = (NS == 1 || blockIdx.z == 0) ? bias[gcol] : 0.f;
#pragma unroll
        for (int i = 0; i < 2; i++) {
#pragma unroll
            for (int r = 0; r < 4; r++) {
                const int grow = m0 + wm + i * 16 + erow + r;
                float v = acc[i][j][r] + bv;
                if (EPI == 1) v = v * 0.5f * (1.0f + erff(v * 0.70710678118654752f));
                if (OUTBF)
                    ((ushort*)Cout)[(size_t)grow * N + gcol] = f2bu(v);
                else
                    outF[(size_t)grow * N + gcol] = v;
            }
        }
    }
}

// ---------------------------------------------------------------------------
// MFMA flash attention with register-staged double-buffered K/V (T14).
// ---------------------------------------------------------------------------
#define VST 68

__global__ __launch_bounds__(256) void flash_attn_mfma_kernel(
    const ushort* __restrict__ QKV, const int* __restrict__ amask,
    __hip_bfloat16* __restrict__ Octx)
{
    const int q0 = blockIdx.x * 64, h = blockIdx.y, b = blockIdx.z;
    const int tid = threadIdx.x, lane = tid & 63, wave = tid >> 6;
    __shared__ ushort Qs[64 * VST];          // [q][d]
    __shared__ ushort Ks[2][64 * VST];       // [key][d] x2
    __shared__ ushort Vt[2][64 * VST];       // [d][key] x2
    __shared__ ushort Ps[4][16 * VST];       // per-wave [q][key]
    __shared__ float biasS[S_];

    for (int i = tid; i < S_; i += 256)
        biasS[i] = amask[b * S_ + i] ? 0.f : -1e9f;

    // staging index maps
    const int ky = tid >> 2, dg = (tid & 3) * 16;   // K: row ky, d-group dg
    const int dd = tid & 63, kg = tid >> 6;         // V: d=dd, key-group kg

    const ushort* kbase = QKV + (size_t)b * S_ * QKVN + H_ + h * DH_;
    const ushort* vbase = QKV + (size_t)b * S_ * QKVN + 2 * H_ + h * DH_;

    s16x8 kr0, kr1;
    ushort2 vr[8];

#define LOAD_KV(kt)                                                          \
    {                                                                        \
        const ushort* kb = kbase + (size_t)((kt) + ky) * QKVN;               \
        kr0 = *(const s16x8*)(kb + dg);                                      \
        kr1 = *(const s16x8*)(kb + dg + 8);                                  \
        const ushort* vb = vbase + (size_t)(kt) * QKVN + dd;                 \
        _Pragma("unroll")                                                    \
        for (int kp = 0; kp < 8; kp++) {                                     \
            const int key = kg * 16 + kp * 2;                                \
            vr[kp].x = vb[(size_t)key * QKVN];                               \
            vr[kp].y = vb[(size_t)(key + 1) * QKVN];                         \
        }                                                                    \
    }

#define STORE_KV(buf)                                                        \
    {                                                                        \
        ushort* dk = &Ks[buf][ky * VST + dg];                                \
        *(s16x4v*)(dk)      = __builtin_shufflevector(kr0, kr0, 0, 1, 2, 3); \
        *(s16x4v*)(dk + 4)  = __builtin_shufflevector(kr0, kr0, 4, 5, 6, 7); \
        *(s16x4v*)(dk + 8)  = __builtin_shufflevector(kr1, kr1, 0, 1, 2, 3); \
        *(s16x4v*)(dk + 12) = __builtin_shufflevector(kr1, kr1, 4, 5, 6, 7); \
        _Pragma("unroll")                                                    \
        for (int kp = 0; kp < 8; kp++)                                       \
            *(ushort2*)&Vt[buf][dd * VST + kg * 16 + kp * 2] = vr[kp];       \
    }

    {   // stage Q
        const ushort* qb = QKV + (size_t)(b * S_ + q0) * QKVN + h * DH_;
        const int q = tid >> 2;
        s16x8 v0 = *(const s16x8*)(qb + (size_t)q * QKVN + dg);
        s16x8 v1 = *(const s16x8*)(qb + (size_t)q * QKVN + dg + 8);
        ushort* d = &Qs[q * VST + dg];
        *(s16x4v*)(d)      = __builtin_shufflevector(v0, v0, 0, 1, 2, 3);
        *(s16x4v*)(d + 4)  = __builtin_shufflevector(v0, v0, 4, 5, 6, 7);
        *(s16x4v*)(d + 8)  = __builtin_shufflevector(v1, v1, 0, 1, 2, 3);
        *(s16x4v*)(d + 12) = __builtin_shufflevector(v1, v1, 4, 5, 6, 7);
    }
    LOAD_KV(0);
    STORE_KV(0);
    __syncthreads();            // Q + bias + buffer 0 visible

    const int fm = lane & 15;
    const int fk = (lane >> 4) * 8;

    const s16x8 aq0 = lds_frag(&Qs[(wave * 16 + fm) * VST + fk]);
    const s16x8 aq1 = lds_frag(&Qs[(wave * 16 + fm) * VST + 32 + fk]);

    f32x4 acc[4];
#pragma unroll
    for (int j = 0; j < 4; j++) acc[j] = (f32x4){0.f, 0.f, 0.f, 0.f};
    float m_i[4], l_i[4];
#pragma unroll
    for (int r = 0; r < 4; r++) { m_i[r] = -INFINITY; l_i[r] = 0.f; }

    int cur = 0;
    for (int ti = 0; ti < S_ / 64; ti++) {
        const int kt = ti * 64;
        if (ti + 1 < S_ / 64) LOAD_KV(kt + 64);   // in flight during compute

        const ushort* Ksc = Ks[cur];
        const ushort* Vtc = Vt[cur];

        f32x4 sc[4];
        __builtin_amdgcn_s_setprio(1);
#pragma unroll
        for (int jj = 0; jj < 4; jj++) {
            s16x8 b0 = lds_frag(&Ksc[(jj * 16 + fm) * VST + fk]);
            s16x8 b1 = lds_frag(&Ksc[(jj * 16 + fm) * VST + 32 + fk]);
            f32x4 z = (f32x4){0.f, 0.f, 0.f, 0.f};
            z = __builtin_amdgcn_mfma_f32_16x16x32_bf16(aq0, b0, z, 0, 0, 0);
            z = __builtin_amdgcn_mfma_f32_16x16x32_bf16(aq1, b1, z, 0, 0, 0);
            sc[jj] = z;
        }
        __builtin_amdgcn_s_setprio(0);

#pragma unroll
        for (int r = 0; r < 4; r++) {
            float mx = -INFINITY;
#pragma unroll
            for (int jj = 0; jj < 4; jj++) {
                float v = sc[jj][r] * 0.125f + biasS[kt + jj * 16 + fm];
                sc[jj][r] = v;
                mx = fmaxf(mx, v);
            }
#pragma unroll
            for (int msk = 1; msk < 16; msk <<= 1) mx = fmaxf(mx, __shfl_xor(mx, msk));
            const float newm = fmaxf(m_i[r], mx);
            const float alpha = __expf(m_i[r] - newm);
            m_i[r] = newm;
            float rs = 0.f;
#pragma unroll
            for (int jj = 0; jj < 4; jj++) {
                float p = __expf(sc[jj][r] - newm);
                sc[jj][r] = p; rs += p;
            }
#pragma unroll
            for (int msk = 1; msk < 16; msk <<= 1) rs += __shfl_xor(rs, msk);
            l_i[r] = l_i[r] * alpha + rs;
#pragma unroll
            for (int jj = 0; jj < 4; jj++) acc[jj][r] *= alpha;
        }

        ushort* const Pw = &Ps[wave][0];
#pragma unroll
        for (int jj = 0; jj < 4; jj++)
#pragma unroll
            for (int r = 0; r < 4; r++)
                Pw[((lane >> 4) * 4 + r) * VST + jj * 16 + fm] = f2bu(sc[jj][r]);

        const s16x8 ap0 = lds_frag(&Pw[fm * VST + fk]);
        const s16x8 ap1 = lds_frag(&Pw[fm * VST + 32 + fk]);

        __builtin_amdgcn_s_setprio(1);
#pragma unroll
        for (int jj = 0; jj < 4; jj++) {
            s16x8 b0 = lds_frag(&Vtc[(jj * 16 + fm) * VST + fk]);
            s16x8 b1 = lds_frag(&Vtc[(jj * 16 + fm) * VST + 32 + fk]);
            acc[jj] = __builtin_amdgcn_mfma_f32_16x16x32_bf16(ap0, b0, acc[jj], 0, 0, 0);
            acc[jj] = __builtin_amdgcn_mfma_f32_16x16x32_bf16(ap1, b1, acc[jj], 0, 0, 0);
        }
        __builtin_amdgcn_s_setprio(0);

        if (ti + 1 < S_ / 64) {
            STORE_KV(cur ^ 1);   // cur^1 last read at tile ti-1; safe
            __syncthreads();     // publish buffer cur^1
        }
        cur ^= 1;
    }
#undef LOAD_KV
#undef STORE_KV

#pragma unroll
    for (int r = 0; r < 4; r++) {
        const int q = q0 + wave * 16 + (lane >> 4) * 4 + r;
        const float inv = 1.0f / l_i[r];
        __hip_bfloat16* op = Octx + (size_t)(b * S_ + q) * H_ + h * DH_;
#pragma unroll
        for (int jj = 0; jj < 4; jj++)
            op[jj * 16 + fm] = __float2bfloat16(acc[jj][r] * inv);
    }
}

// ---------------------------------------------------------------------------
// x = LN(x + sum of NS delta slabs) in place; writes bf16 shadow xb.
// QA=1: fuse the QA head into the same pass.
// ---------------------------------------------------------------------------
template<int NS, int QA>
__global__ __launch_bounds__(256) void add_ln_kernel(
    float* __restrict__ x, const float* __restrict__ delta,
    const float* __restrict__ g, const float* __restrict__ bb,
    __hip_bfloat16* __restrict__ xb,
    const float* __restrict__ qa_w, const float* __restrict__ qa_b,
    float* __restrict__ em)
{
    const int t = blockIdx.x;
    const int tid = threadIdx.x;
    __shared__ float red[256];
    __shared__ float red2[256];
    const size_t base = (size_t)t * H_;

    float v[3];
    float sum = 0.f;
#pragma unroll
    for (int i = 0; i < 3; i++) {
        int c = tid + i * 256;
        float d = x[base + c];
#pragma unroll
        for (int s = 0; s < NS; s++)
            d += delta[(size_t)s * M_ * H_ + base + c];
        v[i] = d;
        sum += d;
    }
    red[tid] = sum; __syncthreads();
    for (int st = 128; st > 0; st >>= 1) { if (tid < st) red[tid] += red[tid + st]; __syncthreads(); }
    const float mean = red[0] / (float)H_;
    __syncthreads();
    float s2 = 0.f;
#pragma unroll
    for (int i = 0; i < 3; i++) { float d = v[i] - mean; s2 += d * d; }
    red[tid] = s2; __syncthreads();
    for (int st = 128; st > 0; st >>= 1) { if (tid < st) red[tid] += red[tid + st]; __syncthreads(); }
    const float rstd = rsqrtf(red[0] / (float)H_ + 1e-12f);
    float s0 = 0.f, s1 = 0.f;
#pragma unroll
    for (int i = 0; i < 3; i++) {
        int c = tid + i * 256;
        float o = (v[i] - mean) * rstd * g[c] + bb[c];
        x[base + c] = o;
        xb[base + c] = __float2bfloat16(o);
        if (QA) {
            s0 += o * qa_w[c * 2 + 0];
            s1 += o * qa_w[c * 2 + 1];
        }
    }
    if (QA) {
        __syncthreads();
        red[tid] = s0; red2[tid] = s1; __syncthreads();
        for (int st = 128; st > 0; st >>= 1) {
            if (tid < st) { red[tid] += red[tid + st]; red2[tid] += red2[tid + st]; }
            __syncthreads();
        }
        if (tid == 0) {
            em[(size_t)t * 2 + 0] = red[0] + qa_b[0];
            em[(size_t)t * 2 + 1] = red2[0] + qa_b[1];
        }
    }
}

// ---------------------------------------------------------------------------
// CRF via log-semiring parallel reduction (unchanged).
// ---------------------------------------------------------------------------
__device__ __forceinline__ float lse2(float a, float b) {
    float m = fmaxf(a, b);
    return m + log1pf(expf(-fabsf(a - b)));
}

__device__ __forceinline__ float4 lsem_comb(float4 a, float4 b) {
    float4 r;
    r.x = lse2(a.x + b.x, a.y + b.z);
    r.y = lse2(a.x + b.y, a.y + b.w);
    r.z = lse2(a.z + b.x, a.w + b.z);
    r.w = lse2(a.z + b.y, a.w + b.w);
    return r;
}

__global__ __launch_bounds__(256) void crf_parallel_kernel(
    const float* __restrict__ em, const int* __restrict__ amask,
    const int* __restrict__ spos, const int* __restrict__ epos,
    const float* __restrict__ startT, const float* __restrict__ endT,
    const float* __restrict__ trans, float* __restrict__ out)
{
    __shared__ float4 mats[B_][64];
    __shared__ float numred[B_][64];
    __shared__ float cntred[B_][64];
    __shared__ float llh[B_];
    const int tid = threadIdx.x;
    const int s = tid >> 6;
    const int j = tid & 63;
    const float NEG = -1e30f;

    const int sp = spos[s], ep = epos[s];
    const bool valid = (sp >= 0) && (sp < S_) && (ep >= 0) && (ep < S_) && (sp <= ep);
    const float* e = em + (size_t)s * S_ * 2;
    const int* mk = amask + s * S_;
    const float t00 = trans[0], t01 = trans[1], t10 = trans[2], t11 = trans[3];

    float4 C = make_float4(0.f, NEG, NEG, 0.f);
    float num = 0.f, cnt = 0.f;
#pragma unroll
    for (int k = 0; k < 8; k++) {
        const int t = j * 8 + 1 + k;
        float4 Mt = make_float4(0.f, NEG, NEG, 0.f);
        if (t < S_ && mk[t]) {
            const float e0 = e[2 * t], e1 = e[2 * t + 1];
            Mt = make_float4(t00 + e0, t01 + e1, t10 + e0, t11 + e1);
            const int tp = (valid && (t - 1) >= sp && (t - 1) <= ep) ? 1 : 0;
            const int tc = (valid && t >= sp && t <= ep) ? 1 : 0;
            const float tr = tp ? (tc ? t11 : t10) : (tc ? t01 : t00);
            num += tr + (tc ? e1 : e0);
            cnt += 1.f;
        }
        C = (k == 0) ? Mt : lsem_comb(C, Mt);
    }
    if (j == 0) {
        const int tag0 = (valid && 0 >= sp && 0 <= ep) ? 1 : 0;
        num += startT[tag0] + e[tag0];
        cnt += mk[0] ? 1.f : 0.f;
    }
    mats[s][j] = C;
    numred[s][j] = num;
    cntred[s][j] = cnt;
    __syncthreads();

    for (int st = 32; st >= 1; st >>= 1) {
        float4 a, b;
        const bool act = (j < st);
        if (act) { a = mats[s][2 * j]; b = mats[s][2 * j + 1]; }
        __syncthreads();
        if (act) mats[s][j] = lsem_comb(a, b);
        __syncthreads();
    }
    for (int st = 32; st >= 1; st >>= 1) {
        if (j < st) {
            numred[s][j] += numred[s][j + st];
            cntred[s][j] += cntred[s][j + st];
        }
        __syncthreads();
    }

    if (j == 0) {
        float numT = numred[s][0];
        const int last_idx = (int)(cntred[s][0] + 0.5f) - 1;
        const int ltag = (valid && last_idx >= sp && last_idx <= ep) ? 1 : 0;
        numT += endT[ltag];
        const float a00 = startT[0] + e[0];
        const float a01 = startT[1] + e[1];
        const float4 P = mats[s][0];
        const float aF0 = lse2(a00 + P.x, a01 + P.z);
        const float aF1 = lse2(a00 + P.y, a01 + P.w);
        const float logZ = lse2(aF0 + endT[0], aF1 + endT[1]);
        llh[s] = numT - logZ;
    }
    __syncthreads();
    if (tid == 0)
        out[0] = -(llh[0] + llh[1] + llh[2] + llh[3]);
}

// ---------------------------------------------------------------------------
// Launch
// ---------------------------------------------------------------------------
extern "C" void kernel_launch(void* const* d_in, const int* in_sizes, int n_in,
                              void* d_out, int out_size, void* d_ws, size_t ws_size,
                              hipStream_t stream)
{
    const int*   input_ids  = (const int*)  d_in[0];
    const int*   attn_mask  = (const int*)  d_in[1];
    const int*   token_type = (const int*)  d_in[2];
    const int*   start_pos  = (const int*)  d_in[3];
    const int*   end_pos    = (const int*)  d_in[4];
    const float* word_emb   = (const float*)d_in[5];
    const float* pos_emb    = (const float*)d_in[6];
    const float* type_emb   = (const float*)d_in[7];
    const float* emb_ln_g   = (const float*)d_in[8];
    const float* emb_ln_b   = (const float*)d_in[9];
    const float* Wq         = (const float*)d_in[10];
    const float* bq         = (const float*)d_in[11];
    const float* Wk         = (const float*)d_in[12];
    const float* bk         = (const float*)d_in[13];
    const float* Wv         = (const float*)d_in[14];
    const float* bv         = (const float*)d_in[15];
    const float* Wo         = (const float*)d_in[16];
    const float* bo         = (const float*)d_in[17];
    const float* ln1_g      = (const float*)d_in[18];
    const float* ln1_b      = (const float*)d_in[19];
    const float* W1         = (const float*)d_in[20];
    const float* b1         = (const float*)d_in[21];
    const float* W2         = (const float*)d_in[22];
    const float* b2         = (const float*)d_in[23];
    const float* ln2_g      = (const float*)d_in[24];
    const float* ln2_b      = (const float*)d_in[25];
    const float* qa_w       = (const float*)d_in[26];
    const float* qa_b       = (const float*)d_in[27];
    const float* crf_start  = (const float*)d_in[28];
    const float* crf_end    = (const float*)d_in[29];
    const float* crf_trans  = (const float*)d_in[30];
    float* out = (float*)d_out;

    // Workspace carve-up
    float*  x      = (float*)d_ws;                                  // M*H
    float*  tmp768 = x + (size_t)M_ * H_;                           // 4 * M*H (split-K slabs)
    float*  emis   = tmp768 + (size_t)4 * M_ * H_;                  // M*2
    float*  b_qkv  = emis + (size_t)M_ * 2;                         // L*2304
    ushort* xb     = (ushort*)(b_qkv + (size_t)L_ * QKVN);          // M*H
    ushort* qkvb   = xb + (size_t)M_ * H_;                          // M*2304
    ushort* ctxb   = qkvb + (size_t)M_ * QKVN;                      // M*H
    ushort* hb     = ctxb + (size_t)M_ * H_;                        // M*FF
    ushort* Wt_qkv = hb + (size_t)M_ * FF_;                         // L*2304*768 (tiled)
    ushort* Wt_o   = Wt_qkv + (size_t)L_ * QKVN * H_;               // L*768*768  (tiled)
    ushort* Wt_1   = Wt_o + (size_t)L_ * H_ * H_;                   // L*768*3072 (tiled)
    ushort* Wt_2   = Wt_1 + (size_t)L_ * H_ * FF_;                  // L*3072*768 (tiled)

    dim3 blk(256);

    // all-layer weight prep + embedding in one launch
    prep_embed_kernel<<<dim3(2048, L_ + 1), blk, 0, stream>>>(
        Wq, Wk, Wv, Wo, W1, W2, bq, bk, bv,
        Wt_qkv, Wt_o, Wt_1, Wt_2, b_qkv,
        input_ids, token_type, word_emb, pos_emb, type_emb,
        emb_ln_g, emb_ln_b, x, (__hip_bfloat16*)xb);

    const dim3 gQKV(QKVN / TN, M_ / TM);      // 18 x 32
    const dim3 gO(H_ / TN, M_ / TM, 2);       //  6 x 32 x 2 (split-K)
    const dim3 gF1(FF_ / TN, M_ / TM);        // 24 x 32
    const dim3 gF2(H_ / TN, M_ / TM, 4);      //  6 x 32 x 4 (split-K)
    const dim3 gA(S_ / 64, NH_, B_);          //  8 x 12 x 4

    for (int l = 0; l < L_; l++) {
        gemm_mfma_kernel<0, 1, 1><<<gQKV, blk, 0, stream>>>(
            xb, Wt_qkv + (size_t)l * QKVN * H_, b_qkv + (size_t)l * QKVN,
            qkvb, M_, H_, QKVN);

        flash_attn_mfma_kernel<<<gA, blk, 0, stream>>>(
            qkvb, attn_mask, (__hip_bfloat16*)ctxb);

        gemm_mfma_kernel<0, 0, 2><<<gO, blk, 0, stream>>>(
            ctxb, Wt_o + (size_t)l * H_ * H_, bo + l * H_, tmp768, M_, H_, H_);
        add_ln_kernel<2, 0><<<M_, blk, 0, stream>>>(
            x, tmp768, ln1_g + l * H_, ln1_b + l * H_,
            (__hip_bfloat16*)xb, nullptr, nullptr, nullptr);

        gemm_mfma_kernel<1, 1, 1><<<gF1, blk, 0, stream>>>(
            xb, Wt_1 + (size_t)l * H_ * FF_, b1 + l * FF_, hb, M_, H_, FF_);
        gemm_mfma_kernel<0, 0, 4><<<gF2, blk, 0, stream>>>(
            hb, Wt_2 + (size_t)l * FF_ * H_, b2 + l * H_, tmp768, M_, FF_, H_);
        if (l == L_ - 1)
            add_ln_kernel<4, 1><<<M_, blk, 0, stream>>>(
                x, tmp768, ln2_g + l * H_, ln2_b + l * H_,
                (__hip_bfloat16*)xb, qa_w, qa_b, emis);
        else
            add_ln_kernel<4, 0><<<M_, blk, 0, stream>>>(
                x, tmp768, ln2_g + l * H_, ln2_b + l * H_,
                (__hip_bfloat16*)xb, nullptr, nullptr, nullptr);
    }

    crf_parallel_kernel<<<1, 256, 0, stream>>>(emis, attn_mask, start_pos, end_pos,
                                               crf_start, crf_end, crf_trans, out);
}